// Round 3
// baseline (769.947 us; speedup 1.0000x reference)
//
#include <hip/hip_runtime.h>
#include <hip/hip_bf16.h>
#include <stdint.h>

// ---------- constants ----------
#define BATCH 64
#define CC 384
#define NHEAD 12
#define KD 32
#define NTOK 49
#define LL 784
#define MTOT 50176        // BATCH*LL = 1024 windows * 49
#define HID 1536
#define QKV_OUT 1152
#define SCALE 0.17677669529663687f
#define EPS 1e-5f

typedef __bf16 bf16x8 __attribute__((ext_vector_type(8)));
typedef float f32x4 __attribute__((ext_vector_type(4)));

__device__ __forceinline__ float bf2f(unsigned short u) {
  union { unsigned int u; float f; } cv; cv.u = ((unsigned int)u) << 16; return cv.f;
}
__device__ __forceinline__ unsigned short f2bf(float f) {
  union { float f; unsigned int u; } cv; cv.f = f;
  unsigned int r = cv.u + 0x7FFFu + ((cv.u >> 16) & 1u);
  return (unsigned short)(r >> 16);
}
__device__ __forceinline__ void gl_lds16(const unsigned short* g, unsigned short* l) {
  __builtin_amdgcn_global_load_lds(
      (const __attribute__((address_space(1))) unsigned int*)g,
      (__attribute__((address_space(3))) unsigned int*)l, 16, 0, 0);
}

// ---------- dtype detection (bf16 vs fp32 wire format) ----------
__global__ void detect_kernel(const unsigned short* __restrict__ x, int* flag) {
  __shared__ int cnt;
  if (threadIdx.x == 0) cnt = 0;
  __syncthreads();
  int c = 0;
  for (int i = threadIdx.x; i < 4096; i += 256) {
    if (((x[i] >> 7) & 0xFF) == 0xFF) c++;
  }
  atomicAdd(&cnt, c);
  __syncthreads();
  if (threadIdx.x == 0) *flag = (cnt > 0) ? 1 : 0;
}

// ---------- input canonicalization (vectorized) ----------
struct CvtArgs {
  const void* src[19];
  unsigned int n[19];
  unsigned int off[19];
};
__global__ __launch_bounds__(256) void convert_kernel(
    CvtArgs a, unsigned short* __restrict__ dst, const int* __restrict__ flag) {
  const int which = blockIdx.y;
  const unsigned int nn = a.n[which];
  unsigned short* d = dst + a.off[which];
  const unsigned int stride = gridDim.x * blockDim.x;
  const unsigned int idx = blockIdx.x * blockDim.x + threadIdx.x;
  const unsigned int ng = nn >> 3;
  if (*flag) {
    const float* s = (const float*)a.src[which];
    for (unsigned int g = idx; g < ng; g += stride) {
      const float4 f0 = ((const float4*)s)[g * 2];
      const float4 f1 = ((const float4*)s)[g * 2 + 1];
      ushort4 lo, hi;
      lo.x = f2bf(f0.x); lo.y = f2bf(f0.y); lo.z = f2bf(f0.z); lo.w = f2bf(f0.w);
      hi.x = f2bf(f1.x); hi.y = f2bf(f1.y); hi.z = f2bf(f1.z); hi.w = f2bf(f1.w);
      ((ushort4*)d)[g * 2] = lo;
      ((ushort4*)d)[g * 2 + 1] = hi;
    }
    for (unsigned int i = ng * 8 + idx; i < nn; i += stride) d[i] = f2bf(s[i]);
  } else {
    const unsigned short* s = (const unsigned short*)a.src[which];
    for (unsigned int g = idx; g < ng; g += stride)
      ((uint4*)d)[g] = ((const uint4*)s)[g];
    for (unsigned int i = ng * 8 + idx; i < nn; i += stride) d[i] = s[i];
  }
}

// ---------- bias table precompute: bias_full[h][n][m] fp32 ----------
__global__ __launch_bounds__(256) void bias_kernel(
    const unsigned short* __restrict__ cAb, const int* __restrict__ bias_idxs,
    float* __restrict__ bias_full) {
  const int h = blockIdx.x;
  for (int i = threadIdx.x; i < NTOK * NTOK; i += 256)
    bias_full[h * NTOK * NTOK + i] = bf2f(cAb[h * NTOK + bias_idxs[i]]);
}

// ---------- conv/BN table precompute: cwT[t][c] bf16, bn scale/shift fp32 ----------
__global__ __launch_bounds__(384) void prep_kernel(
    const unsigned short* __restrict__ cw, const unsigned short* __restrict__ bg,
    const unsigned short* __restrict__ bb, const unsigned short* __restrict__ bm,
    const unsigned short* __restrict__ bv,
    unsigned short* __restrict__ cwT, float* __restrict__ bnsc, float* __restrict__ bnsh) {
  const int c = threadIdx.x;
  const float sc = bf2f(bg[c]) * rsqrtf(bf2f(bv[c]) + EPS);
  bnsc[c] = sc;
  bnsh[c] = bf2f(bb[c]) - bf2f(bm[c]) * sc;
  #pragma unroll
  for (int t = 0; t < 9; ++t) cwT[t * CC + c] = cw[c * 9 + t];
}

// ---------- LayerNorm + window gather (pre-attention) ----------
__global__ __launch_bounds__(128) void ln_kernel(
    const unsigned short* __restrict__ x, const unsigned short* __restrict__ g,
    const unsigned short* __restrict__ b, unsigned short* __restrict__ out) {
  const int tid = threadIdx.x;
  int wi = blockIdx.y, n = blockIdx.x;
  int bb = wi >> 4, wb = wi & 15;
  int nh_i = wb >> 2, nw_i = wb & 3;
  int hs = n / 7, wsx = n - hs * 7;
  int l = nh_i * 196 + hs * 28 + nw_i * 7 + wsx;
  size_t src_row = (size_t)bb * LL + l;
  size_t dst_row = (size_t)wi * NTOK + n;
  const unsigned short* xr = x + src_row * CC;
  float vals[3]; float s = 0.f, sq = 0.f;
  for (int j = 0; j < 3; ++j) {
    vals[j] = bf2f(xr[tid + 128 * j]);
    s += vals[j]; sq += vals[j] * vals[j];
  }
  for (int off = 32; off; off >>= 1) { s += __shfl_xor(s, off); sq += __shfl_xor(sq, off); }
  __shared__ float red[4];
  const int wv = tid >> 6;
  if ((tid & 63) == 0) { red[wv] = s; red[2 + wv] = sq; }
  __syncthreads();
  float tot = red[0] + red[1], totq = red[2] + red[3];
  float mean = tot * (1.f / CC);
  float var = totq * (1.f / CC) - mean * mean;
  float inv = rsqrtf(var + EPS);
  unsigned short* orow = out + dst_row * CC;
  for (int j = 0; j < 3; ++j) {
    int c = tid + 128 * j;
    float y = (vals[j] - mean) * inv * bf2f(g[c]) + bf2f(b[c]);
    orow[c] = f2bf(y);
  }
}

// ---------- GEMM: 128x128 tile, 4 waves, 4x4 acc, BK=64 ----------
// K-loop: 2 LDS buffers (32KB each), BK=64 (half the barriers of BK=32),
// counted s_waitcnt vmcnt(8) (T4: next tile's 8 loads stay in flight).
// T2 swizzle (rule #21 both-sides): row = 128B = 8 x 16B granules; stage
// reads global col (c ^ (row&7))*8 into linear LDS granule (row,c); reader
// computes granule ((kk/8+quad) ^ (fr&7)). 16 lanes/quad now spread across
// all 8 bank-groups -> 2-way conflict = free (was 8-way at row=64B).
enum { EP_PLAIN = 0, EP_GELU = 1, EP_WINRES = 2, EP_RES2 = 3 };

template <int EP>
__global__ __launch_bounds__(256) void gemm128(
    const unsigned short* __restrict__ A, const unsigned short* __restrict__ W,
    const unsigned short* __restrict__ bias, const unsigned short* __restrict__ res,
    void* __restrict__ outp, int K, int N, int m_off, const int* __restrict__ flagp) {
  __shared__ __align__(16) unsigned short lds[2 * 16384];  // 2 x (A 128x64 + B 128x64)
  const int tid = threadIdx.x;
  const int lane = tid & 63;
  const int wave = tid >> 6;
  const int bm = blockIdx.x * 128;
  const int bn = blockIdx.y * 128;
  const int wm = (wave >> 1) * 64;
  const int wn = (wave & 1) * 64;
  // staging: granule g = row*8 + c ; thread handles g = tid + 256*j
  // (rows (tid>>3) + 32j), source col XOR-swizzled.
  const int g_row = tid >> 3;                   // 0..31
  const int g_c   = tid & 7;
  const int s_col = (g_c ^ (g_row & 7)) * 8;    // swizzled source col (shorts)
  const unsigned short* Ap0 = A + (size_t)(bm + g_row) * K + s_col;
  const unsigned short* Wp0 = W + (size_t)(bn + g_row) * K + s_col;
  const size_t rstep32 = (size_t)32 * K;
  f32x4 acc[4][4] = {};
  const int fr = lane & 15;
  const int quad = lane >> 4;
  const int nt = K >> 6;   // K % 64 == 0 for all GEMMs here (384, 1536)
  // read addressing (shorts): row stride 64 shorts; swizzled granule cols
  const int rs_a = (wm + fr) * 64;
  const int rs_b = (wn + fr) * 64;
  const int cg0 = (quad ^ (fr & 7)) * 8;        // k-half 0
  const int cg1 = ((4 + quad) ^ (fr & 7)) * 8;  // k-half 1

  auto stage = [&](int bsel, int t) {
    const unsigned short* ap = Ap0 + (size_t)t * 64;
    const unsigned short* wp = Wp0 + (size_t)t * 64;
    unsigned short* al = lds + bsel * 16384 + tid * 8;
    unsigned short* bl = al + 8192;
    #pragma unroll
    for (int j = 0; j < 4; ++j) {
      gl_lds16(ap + j * rstep32, al + j * 2048);
      gl_lds16(wp + j * rstep32, bl + j * 2048);
    }
  };

  stage(0, 0);
  for (int t = 0; t < nt; ++t) {
    const int cb = t & 1;
    if (t + 1 < nt) {
      stage(cb ^ 1, t + 1);   // overwrite of buf^1 is safe: its readers
                              // passed the end-of-iter-(t-1) barrier
      asm volatile("s_waitcnt vmcnt(8)" ::: "memory");  // retire tile t's 8
    } else {
      asm volatile("s_waitcnt vmcnt(0)" ::: "memory");
    }
    __builtin_amdgcn_s_barrier();              // tile t resident for all waves
    __builtin_amdgcn_sched_barrier(0);         // don't hoist ds_reads above
    const unsigned short* Ab = lds + cb * 16384;
    const unsigned short* Bb = Ab + 8192;
    bf16x8 af0[4], af1[4], bf0[4], bf1[4];
    #pragma unroll
    for (int i = 0; i < 4; ++i) {
      af0[i] = *(const bf16x8*)(Ab + rs_a + i * 1024 + cg0);
      af1[i] = *(const bf16x8*)(Ab + rs_a + i * 1024 + cg1);
      bf0[i] = *(const bf16x8*)(Bb + rs_b + i * 1024 + cg0);
      bf1[i] = *(const bf16x8*)(Bb + rs_b + i * 1024 + cg1);
    }
    #pragma unroll
    for (int i = 0; i < 4; ++i)
      #pragma unroll
      for (int j = 0; j < 4; ++j) {
        acc[i][j] = __builtin_amdgcn_mfma_f32_16x16x32_bf16(af0[i], bf0[j], acc[i][j], 0, 0, 0);
        acc[i][j] = __builtin_amdgcn_mfma_f32_16x16x32_bf16(af1[i], bf1[j], acc[i][j], 0, 0, 0);
      }
    asm volatile("s_waitcnt lgkmcnt(0)" ::: "memory");  // my reads retired
    __builtin_amdgcn_sched_barrier(0);
    __builtin_amdgcn_s_barrier();              // all waves done reading buf t
  }

  int isf32 = 0;
  if (EP == EP_RES2) isf32 = *flagp;
  const int qr = (lane >> 4) * 4;
  float bvs[4];
  #pragma unroll
  for (int tj = 0; tj < 4; ++tj) bvs[tj] = bf2f(bias[bn + wn + tj * 16 + fr]);
  #pragma unroll
  for (int ti = 0; ti < 4; ++ti) {
    #pragma unroll
    for (int r = 0; r < 4; ++r) {
      const int mr = bm + wm + ti * 16 + qr + r;
      size_t rowbase;
      if (EP == EP_WINRES) {
        int wi = mr / 49; int nt2 = mr - wi * 49;
        int bb = wi >> 4; int wb = wi & 15;
        int nh_i = wb >> 2; int nw_i = wb & 3;
        int hs = nt2 / 7; int wsx = nt2 - hs * 7;
        int l = nh_i * 196 + hs * 28 + nw_i * 7 + wsx;
        rowbase = ((size_t)bb * LL + l) * CC;
      } else if (EP == EP_RES2) {
        rowbase = (size_t)(mr + m_off) * N;
      } else {
        rowbase = (size_t)mr * N;
      }
      #pragma unroll
      for (int tj = 0; tj < 4; ++tj) {
        const int n = bn + wn + tj * 16 + fr;
        float v = acc[ti][tj][r] + bvs[tj];
        if (EP == EP_GELU) {
          // gelu(x) = x * sigmoid(1.59576912x + 0.07135482x^3)
          const float t2 = v * (1.5957691216f + 0.0713548162f * v * v);
          v = __fdividef(v, 1.0f + __expf(-t2));
          ((unsigned short*)outp)[rowbase + n] = f2bf(v);
        } else if (EP == EP_WINRES) {
          size_t idx = rowbase + n;
          v += bf2f(res[idx]);
          ((unsigned short*)outp)[idx] = f2bf(v);
        } else if (EP == EP_RES2) {
          size_t idx = rowbase + n;
          v += bf2f(res[idx]);
          if (isf32) ((float*)outp)[idx] = v;
          else       ((unsigned short*)outp)[idx] = f2bf(v);
        } else {
          ((unsigned short*)outp)[rowbase + n] = f2bf(v);
        }
      }
    }
  }
}

// ---------- MFMA windowed attention: one WAVE per (window, head) ----------
__global__ __launch_bounds__(64) void attn_mfma(
    const unsigned short* __restrict__ qkv, const float* __restrict__ bias_full,
    unsigned short* __restrict__ o, int wi_off) {
  __shared__ __align__(16) unsigned short Pl[64 * 72];
  __shared__ __align__(16) unsigned short vT[32 * 72];
  const int wi = blockIdx.x, h = blockIdx.y;
  const int lane = threadIdx.x;
  const int l15 = lane & 15;
  const int quad = lane >> 4;
  const unsigned short* base = qkv + (size_t)wi * NTOK * QKV_OUT + h * 96;

  bf16x8 qf[4], kf[4];
  #pragma unroll
  for (int i = 0; i < 4; ++i) {
    const int n = i * 16 + l15;
    if (n < NTOK) {
      const unsigned short* p = base + (size_t)n * QKV_OUT + quad * 8;
      qf[i] = *(const bf16x8*)(p);
      kf[i] = *(const bf16x8*)(p + 32);
    } else {
      qf[i] = (bf16x8)0; kf[i] = (bf16x8)0;
    }
  }

  for (int idx = lane; idx < 32 * 72; idx += 64) vT[idx] = 0;
  __syncthreads();
  for (int idx = lane; idx < NTOK * KD; idx += 64) {
    const int m = idx >> 5, d = idx & 31;
    vT[d * 72 + m] = base[(size_t)m * QKV_OUT + 64 + d];
  }

  f32x4 acc[4][4] = {};
  #pragma unroll
  for (int i = 0; i < 4; ++i)
    #pragma unroll
    for (int j = 0; j < 4; ++j)
      acc[i][j] = __builtin_amdgcn_mfma_f32_16x16x32_bf16(qf[i], kf[j], acc[i][j], 0, 0, 0);

  const float* bh = bias_full + h * NTOK * NTOK;
  float rinv[4][4];
  #pragma unroll
  for (int i = 0; i < 4; ++i) {
    #pragma unroll
    for (int r = 0; r < 4; ++r) {
      const int n = i * 16 + quad * 4 + r;
      float sv[4];
      #pragma unroll
      for (int j = 0; j < 4; ++j) {
        const int m = j * 16 + l15;
        float s = acc[i][j][r] * SCALE;
        if (n < NTOK && m < NTOK) s += bh[n * NTOK + m];
        if (m >= NTOK) s = -1e30f;
        sv[j] = s;
      }
      float mx = fmaxf(fmaxf(sv[0], sv[1]), fmaxf(sv[2], sv[3]));
      #pragma unroll
      for (int t = 1; t < 16; t <<= 1) mx = fmaxf(mx, __shfl_xor(mx, t));
      float sum = 0.f;
      #pragma unroll
      for (int j = 0; j < 4; ++j) {
        const float p = __expf(sv[j] - mx);
        sum += p;
        Pl[n * 72 + j * 16 + l15] = f2bf(p);
      }
      #pragma unroll
      for (int t = 1; t < 16; t <<= 1) sum += __shfl_xor(sum, t);
      rinv[i][r] = 1.f / sum;
    }
  }
  __syncthreads();

  f32x4 acc2[4][2] = {};
  #pragma unroll
  for (int kk = 0; kk < 2; ++kk) {
    bf16x8 pf[4], vf[2];
    #pragma unroll
    for (int i = 0; i < 4; ++i)
      pf[i] = *(const bf16x8*)(Pl + (i * 16 + l15) * 72 + kk * 32 + quad * 8);
    #pragma unroll
    for (int jd = 0; jd < 2; ++jd)
      vf[jd] = *(const bf16x8*)(vT + (jd * 16 + l15) * 72 + kk * 32 + quad * 8);
    #pragma unroll
    for (int i = 0; i < 4; ++i)
      #pragma unroll
      for (int jd = 0; jd < 2; ++jd)
        acc2[i][jd] = __builtin_amdgcn_mfma_f32_16x16x32_bf16(pf[i], vf[jd], acc2[i][jd], 0, 0, 0);
  }

  #pragma unroll
  for (int i = 0; i < 4; ++i) {
    #pragma unroll
    for (int r = 0; r < 4; ++r) {
      const int n = i * 16 + quad * 4 + r;
      if (n < NTOK) {
        const float ri = rinv[i][r];
        #pragma unroll
        for (int jd = 0; jd < 2; ++jd) {
          const int d = jd * 16 + l15;
          o[((size_t)(wi_off + wi) * NTOK + n) * CC + h * KD + d] = f2bf(acc2[i][jd][r] * ri);
        }
      }
    }
  }
}

// ---------- fused depthwise 3x3 conv + BN + LN_m ----------
__global__ __launch_bounds__(384) void conv_bn_ln(
    const unsigned short* __restrict__ x1, const unsigned short* __restrict__ cwT,
    const float* __restrict__ bnsc, const float* __restrict__ bnsh,
    const unsigned short* __restrict__ mg, const unsigned short* __restrict__ mb,
    unsigned short* __restrict__ x2, unsigned short* __restrict__ xm) {
  __shared__ float rs[8][48], rq[8][48];
  const int tid = threadIdx.x;
  const int pos = tid / 48;
  const int c8 = tid - pos * 48;
  const int c0 = c8 * 8;
  const int hw = blockIdx.x * 8 + pos;
  const int b = blockIdx.y;
  const int h = hw / 28, w = hw - h * 28;
  float acc[8] = {};
  #pragma unroll
  for (int t = 0; t < 9; ++t) {
    const int dh = t / 3 - 1, dw = t % 3 - 1;
    const int hh = h + dh, ww = w + dw;
    if (hh >= 0 && hh < 28 && ww >= 0 && ww < 28) {
      const uint4 xv = *(const uint4*)(x1 + ((size_t)b * LL + hh * 28 + ww) * CC + c0);
      const uint4 wv = *(const uint4*)(cwT + t * CC + c0);
      const unsigned short* xp = (const unsigned short*)&xv;
      const unsigned short* wp = (const unsigned short*)&wv;
      #pragma unroll
      for (int k = 0; k < 8; ++k) acc[k] += bf2f(xp[k]) * bf2f(wp[k]);
    }
  }
  const float4 sc0 = *(const float4*)(bnsc + c0);
  const float4 sc1 = *(const float4*)(bnsc + c0 + 4);
  const float4 sh0 = *(const float4*)(bnsh + c0);
  const float4 sh1 = *(const float4*)(bnsh + c0 + 4);
  float y[8];
  y[0] = acc[0] * sc0.x + sh0.x; y[1] = acc[1] * sc0.y + sh0.y;
  y[2] = acc[2] * sc0.z + sh0.z; y[3] = acc[3] * sc0.w + sh0.w;
  y[4] = acc[4] * sc1.x + sh1.x; y[5] = acc[5] * sc1.y + sh1.y;
  y[6] = acc[6] * sc1.z + sh1.z; y[7] = acc[7] * sc1.w + sh1.w;
  ushort4 pk0, pk1;
  pk0.x = f2bf(y[0]); pk0.y = f2bf(y[1]); pk0.z = f2bf(y[2]); pk0.w = f2bf(y[3]);
  pk1.x = f2bf(y[4]); pk1.y = f2bf(y[5]); pk1.z = f2bf(y[6]); pk1.w = f2bf(y[7]);
  const size_t row = ((size_t)b * LL + hw) * CC + c0;
  *(ushort4*)(x2 + row) = pk0;
  *(ushort4*)(x2 + row + 4) = pk1;
  float s = 0.f, q = 0.f;
  #pragma unroll
  for (int k = 0; k < 8; ++k) { s += y[k]; q += y[k] * y[k]; }
  rs[pos][c8] = s; rq[pos][c8] = q;
  __syncthreads();
  float tot = 0.f, tq = 0.f;
  #pragma unroll 8
  for (int i = 0; i < 48; ++i) { tot += rs[pos][i]; tq += rq[pos][i]; }
  const float mean = tot * (1.f / CC);
  const float var = tq * (1.f / CC) - mean * mean;
  const float inv = rsqrtf(var + EPS);
  const uint4 gv = *(const uint4*)(mg + c0);
  const uint4 bv = *(const uint4*)(mb + c0);
  const unsigned short* gp = (const unsigned short*)&gv;
  const unsigned short* bp = (const unsigned short*)&bv;
  ushort4 lo, hi;
  unsigned short outv[8];
  #pragma unroll
  for (int k = 0; k < 8; ++k)
    outv[k] = f2bf((y[k] - mean) * inv * bf2f(gp[k]) + bf2f(bp[k]));
  lo.x = outv[0]; lo.y = outv[1]; lo.z = outv[2]; lo.w = outv[3];
  hi.x = outv[4]; hi.y = outv[5]; hi.z = outv[6]; hi.w = outv[7];
  *(ushort4*)(xm + row) = lo;
  *(ushort4*)(xm + row + 4) = hi;
}

// ---------- launch ----------
extern "C" void kernel_launch(void* const* d_in, const int* in_sizes, int n_in,
                              void* d_out, int out_size, void* d_ws, size_t ws_size,
                              hipStream_t stream) {
  int* flag = (int*)d_ws;
  unsigned short* base = (unsigned short*)d_ws;

  CvtArgs args;
  size_t cur = 32;
  size_t off[19];
  for (int i = 0; i < 19; ++i) {
    off[i] = cur;
    args.src[i] = d_in[i];
    args.n[i] = (unsigned int)in_sizes[i];
    args.off[i] = (unsigned int)cur;
    cur += ((size_t)in_sizes[i] + 63) & ~(size_t)63;
  }
  const unsigned short* cx   = base + off[0];
  const unsigned short* cgA  = base + off[1];
  const unsigned short* cbA  = base + off[2];
  const unsigned short* cQw  = base + off[3];
  const unsigned short* cQb  = base + off[4];
  const unsigned short* cAb  = base + off[5];
  const unsigned short* cPw  = base + off[6];
  const unsigned short* cPb  = base + off[7];
  const unsigned short* cCw  = base + off[8];
  const unsigned short* cBg  = base + off[9];
  const unsigned short* cBb  = base + off[10];
  const unsigned short* cBm  = base + off[11];
  const unsigned short* cBv  = base + off[12];
  const unsigned short* cMg  = base + off[13];
  const unsigned short* cMb  = base + off[14];
  const unsigned short* cF1w = base + off[15];
  const unsigned short* cF1b = base + off[16];
  const unsigned short* cF2w = base + off[17];
  const unsigned short* cF2b = base + off[18];
  const int* bias_idxs = (const int*)d_in[19];

  const size_t SZ = (size_t)MTOT * CC;             // 19267584 elems
  // chunking: merge M-halves into one launch if workspace permits
  // (2x co-resident waves per GEMM dispatch -> latency hiding).
  const size_t need_full_bytes =
      (cur + SZ + (size_t)MTOT * HID) * 2 + 512 * 1024;
  const int nchunk = (ws_size >= need_full_bytes) ? 1 : 2;
  const int MC = MTOT / nchunk;                    // GEMM rows per chunk
  const int WC = 1024 / nchunk;                    // windows per chunk
  const size_t buf2_cap = (size_t)MC * HID;

  unsigned short* o_buf = base + cur;               // attn out o; later xm
  unsigned short* buf2  = o_buf + SZ;               // qkv chunk / h chunk
  unsigned short* x2    = base + off[0];            // conv+BN out overwrites spent cx
  float* bias_full = (float*)(buf2 + buf2_cap);     // [12][49][49] f32
  unsigned short* cwT = (unsigned short*)(bias_full + 12 * NTOK * NTOK);  // [9][384] bf16
  float* bnsc = (float*)(cwT + 9 * CC);
  float* bnsh = bnsc + CC;

  unsigned short* xn = (unsigned short*)d_out;

  // 0. dtype detect + canonicalize + tables
  detect_kernel<<<1, 256, 0, stream>>>((const unsigned short*)d_in[0], flag);
  convert_kernel<<<dim3(512, 19), 256, 0, stream>>>(args, base, flag);
  bias_kernel<<<NHEAD, 256, 0, stream>>>(cAb, bias_idxs, bias_full);
  prep_kernel<<<1, 384, 0, stream>>>(cCw, cBg, cBb, cBm, cBv, cwT, bnsc, bnsh);

  // 1. window partition + LN_a -> xn (d_out)
  ln_kernel<<<dim3(49, 1024), 128, 0, stream>>>(cx, cgA, cbA, xn);

  // 2+3. qkv projection + MFMA attention
  for (int c = 0; c < nchunk; ++c) {
    gemm128<EP_PLAIN><<<dim3(MC / 128, QKV_OUT / 128), 256, 0, stream>>>(
        xn + (size_t)c * MC * CC, cQw, cQb, nullptr, buf2, CC, QKV_OUT, 0, nullptr);
    attn_mfma<<<dim3(WC, NHEAD), 64, 0, stream>>>(buf2, bias_full, o_buf, c * WC);
  }

  // 4. proj + un-window + residual(x) -> x1 (d_out)
  gemm128<EP_WINRES><<<dim3(MTOT / 128, CC / 128), 256, 0, stream>>>(
      o_buf, cPw, cPb, cx, d_out, CC, CC, 0, nullptr);

  // 5. fused conv + BN + LN_m -> x2 (residual) and xm (o_buf, fc1 input)
  conv_bn_ln<<<dim3(98, BATCH), 384, 0, stream>>>(
      (const unsigned short*)d_out, cwT, bnsc, bnsh, cMg, cMb, x2, o_buf);

  // 6+7. MLP; fc2 writes final output
  for (int c = 0; c < nchunk; ++c) {
    gemm128<EP_GELU><<<dim3(MC / 128, HID / 128), 256, 0, stream>>>(
        o_buf + (size_t)c * MC * CC, cF1w, cF1b, nullptr, buf2, CC, HID, 0, nullptr);
    gemm128<EP_RES2><<<dim3(MC / 128, CC / 128), 256, 0, stream>>>(
        buf2, cF2w, cF2b, x2, d_out, HID, CC, c * MC, flag);
  }
}

// Round 4
// 708.775 us; speedup vs baseline: 1.0863x; 1.0863x over previous
//
#include <hip/hip_runtime.h>
#include <hip/hip_bf16.h>
#include <stdint.h>

// ---------- constants ----------
#define BATCH 64
#define CC 384
#define NHEAD 12
#define KD 32
#define NTOK 49
#define LL 784
#define MTOT 50176        // BATCH*LL = 1024 windows * 49
#define HID 1536
#define QKV_OUT 1152
#define SCALE 0.17677669529663687f
#define EPS 1e-5f

typedef __bf16 bf16x8 __attribute__((ext_vector_type(8)));
typedef float f32x4 __attribute__((ext_vector_type(4)));

__device__ __forceinline__ float bf2f(unsigned short u) {
  union { unsigned int u; float f; } cv; cv.u = ((unsigned int)u) << 16; return cv.f;
}
__device__ __forceinline__ unsigned short f2bf(float f) {
  union { float f; unsigned int u; } cv; cv.f = f;
  unsigned int r = cv.u + 0x7FFFu + ((cv.u >> 16) & 1u);
  return (unsigned short)(r >> 16);
}
__device__ __forceinline__ void gl_lds16(const unsigned short* g, unsigned short* l) {
  __builtin_amdgcn_global_load_lds(
      (const __attribute__((address_space(1))) unsigned int*)g,
      (__attribute__((address_space(3))) unsigned int*)l, 16, 0, 0);
}

// ---------- dtype detection (bf16 vs fp32 wire format) ----------
__global__ void detect_kernel(const unsigned short* __restrict__ x, int* flag) {
  __shared__ int cnt;
  if (threadIdx.x == 0) cnt = 0;
  __syncthreads();
  int c = 0;
  for (int i = threadIdx.x; i < 4096; i += 256) {
    if (((x[i] >> 7) & 0xFF) == 0xFF) c++;
  }
  atomicAdd(&cnt, c);
  __syncthreads();
  if (threadIdx.x == 0) *flag = (cnt > 0) ? 1 : 0;
}

// ---------- input canonicalization (vectorized) ----------
struct CvtArgs {
  const void* src[19];
  unsigned int n[19];
  unsigned int off[19];
};
__global__ __launch_bounds__(256) void convert_kernel(
    CvtArgs a, unsigned short* __restrict__ dst, const int* __restrict__ flag) {
  const int which = blockIdx.y;
  const unsigned int nn = a.n[which];
  unsigned short* d = dst + a.off[which];
  const unsigned int stride = gridDim.x * blockDim.x;
  const unsigned int idx = blockIdx.x * blockDim.x + threadIdx.x;
  const unsigned int ng = nn >> 3;
  if (*flag) {
    const float* s = (const float*)a.src[which];
    for (unsigned int g = idx; g < ng; g += stride) {
      const float4 f0 = ((const float4*)s)[g * 2];
      const float4 f1 = ((const float4*)s)[g * 2 + 1];
      ushort4 lo, hi;
      lo.x = f2bf(f0.x); lo.y = f2bf(f0.y); lo.z = f2bf(f0.z); lo.w = f2bf(f0.w);
      hi.x = f2bf(f1.x); hi.y = f2bf(f1.y); hi.z = f2bf(f1.z); hi.w = f2bf(f1.w);
      ((ushort4*)d)[g * 2] = lo;
      ((ushort4*)d)[g * 2 + 1] = hi;
    }
    for (unsigned int i = ng * 8 + idx; i < nn; i += stride) d[i] = f2bf(s[i]);
  } else {
    const unsigned short* s = (const unsigned short*)a.src[which];
    for (unsigned int g = idx; g < ng; g += stride)
      ((uint4*)d)[g] = ((const uint4*)s)[g];
    for (unsigned int i = ng * 8 + idx; i < nn; i += stride) d[i] = s[i];
  }
}

// ---------- bias table precompute: bias_full[h][n][m] fp32 ----------
__global__ __launch_bounds__(256) void bias_kernel(
    const unsigned short* __restrict__ cAb, const int* __restrict__ bias_idxs,
    float* __restrict__ bias_full) {
  const int h = blockIdx.x;
  for (int i = threadIdx.x; i < NTOK * NTOK; i += 256)
    bias_full[h * NTOK * NTOK + i] = bf2f(cAb[h * NTOK + bias_idxs[i]]);
}

// ---------- conv/BN table precompute: cwT[t][c] bf16, bn scale/shift fp32 ----------
__global__ __launch_bounds__(384) void prep_kernel(
    const unsigned short* __restrict__ cw, const unsigned short* __restrict__ bg,
    const unsigned short* __restrict__ bb, const unsigned short* __restrict__ bm,
    const unsigned short* __restrict__ bv,
    unsigned short* __restrict__ cwT, float* __restrict__ bnsc, float* __restrict__ bnsh) {
  const int c = threadIdx.x;
  const float sc = bf2f(bg[c]) * rsqrtf(bf2f(bv[c]) + EPS);
  bnsc[c] = sc;
  bnsh[c] = bf2f(bb[c]) - bf2f(bm[c]) * sc;
  #pragma unroll
  for (int t = 0; t < 9; ++t) cwT[t * CC + c] = cw[c * 9 + t];
}

// ---------- LayerNorm + window gather (pre-attention) ----------
__global__ __launch_bounds__(128) void ln_kernel(
    const unsigned short* __restrict__ x, const unsigned short* __restrict__ g,
    const unsigned short* __restrict__ b, unsigned short* __restrict__ out) {
  const int tid = threadIdx.x;
  int wi = blockIdx.y, n = blockIdx.x;
  int bb = wi >> 4, wb = wi & 15;
  int nh_i = wb >> 2, nw_i = wb & 3;
  int hs = n / 7, wsx = n - hs * 7;
  int l = nh_i * 196 + hs * 28 + nw_i * 7 + wsx;
  size_t src_row = (size_t)bb * LL + l;
  size_t dst_row = (size_t)wi * NTOK + n;
  const unsigned short* xr = x + src_row * CC;
  float vals[3]; float s = 0.f, sq = 0.f;
  for (int j = 0; j < 3; ++j) {
    vals[j] = bf2f(xr[tid + 128 * j]);
    s += vals[j]; sq += vals[j] * vals[j];
  }
  for (int off = 32; off; off >>= 1) { s += __shfl_xor(s, off); sq += __shfl_xor(sq, off); }
  __shared__ float red[4];
  const int wv = tid >> 6;
  if ((tid & 63) == 0) { red[wv] = s; red[2 + wv] = sq; }
  __syncthreads();
  float tot = red[0] + red[1], totq = red[2] + red[3];
  float mean = tot * (1.f / CC);
  float var = totq * (1.f / CC) - mean * mean;
  float inv = rsqrtf(var + EPS);
  unsigned short* orow = out + dst_row * CC;
  for (int j = 0; j < 3; ++j) {
    int c = tid + 128 * j;
    float y = (vals[j] - mean) * inv * bf2f(g[c]) + bf2f(b[c]);
    orow[c] = f2bf(y);
  }
}

// ---------- GEMM: 128x128 tile, 4 waves, 4x4 acc, BK=64 ----------
// K-loop: 2 LDS buffers, BK=64, counted s_waitcnt vmcnt(8) (T4).
// T2 swizzle (both-sides, rule #21): bank conflicts measured 0 after this.
// Grid is 1D with an XCD-chunked, N-fastest tile mapping (T1 + group-N):
//   wgid = bijective-XCD-chunk(blockIdx.x); bm = (wgid/Nt)*128; bn = (wgid%Nt)*128
// Consecutive blocks on one XCD share the same A-panel (read HBM once, then
// L2-hit) and each XCD owns a contiguous M-range covering all N — fixes the
// round-3 A-refetch (fc2 FETCH 269 MB vs ~190 ideal).
enum { EP_PLAIN = 0, EP_GELU = 1, EP_WINRES = 2, EP_RES2 = 3 };

template <int EP>
__global__ __launch_bounds__(256) void gemm128(
    const unsigned short* __restrict__ A, const unsigned short* __restrict__ W,
    const unsigned short* __restrict__ bias, const unsigned short* __restrict__ res,
    void* __restrict__ outp, int K, int N, int m_off, const int* __restrict__ flagp,
    int Nt) {
  __shared__ __align__(16) unsigned short lds[2 * 16384];  // 2 x (A 128x64 + B 128x64)
  const int tid = threadIdx.x;
  const int lane = tid & 63;
  const int wave = tid >> 6;
  // --- XCD-chunked bijective remap (m204), then N-fastest tile order ---
  const int nwg = gridDim.x;
  const int id = blockIdx.x;
  const int q8 = nwg >> 3, r8 = nwg & 7;
  const int xcd = id & 7, rank = id >> 3;
  const int wgid = (xcd < r8 ? xcd * (q8 + 1) : r8 * (q8 + 1) + (xcd - r8) * q8) + rank;
  const int bm = (wgid / Nt) * 128;
  const int bn = (wgid - (wgid / Nt) * Nt) * 128;
  const int wm = (wave >> 1) * 64;
  const int wn = (wave & 1) * 64;
  // staging: granule g = row*8 + c ; thread handles rows (tid>>3) + 32j,
  // source col XOR-swizzled (LDS dest stays linear for global_load_lds).
  const int g_row = tid >> 3;                   // 0..31
  const int g_c   = tid & 7;
  const int s_col = (g_c ^ (g_row & 7)) * 8;    // swizzled source col (shorts)
  const unsigned short* Ap0 = A + (size_t)(bm + g_row) * K + s_col;
  const unsigned short* Wp0 = W + (size_t)(bn + g_row) * K + s_col;
  const size_t rstep32 = (size_t)32 * K;
  f32x4 acc[4][4] = {};
  const int fr = lane & 15;
  const int quad = lane >> 4;
  const int nt = K >> 6;   // K % 64 == 0 for all GEMMs here (384, 1536)
  // read addressing (shorts): row stride 64 shorts; swizzled granule cols
  const int rs_a = (wm + fr) * 64;
  const int rs_b = (wn + fr) * 64;
  const int cg0 = (quad ^ (fr & 7)) * 8;        // k-half 0
  const int cg1 = ((4 + quad) ^ (fr & 7)) * 8;  // k-half 1

  auto stage = [&](int bsel, int t) {
    const unsigned short* ap = Ap0 + (size_t)t * 64;
    const unsigned short* wp = Wp0 + (size_t)t * 64;
    unsigned short* al = lds + bsel * 16384 + tid * 8;
    unsigned short* bl = al + 8192;
    #pragma unroll
    for (int j = 0; j < 4; ++j) {
      gl_lds16(ap + j * rstep32, al + j * 2048);
      gl_lds16(wp + j * rstep32, bl + j * 2048);
    }
  };

  stage(0, 0);
  for (int t = 0; t < nt; ++t) {
    const int cb = t & 1;
    if (t + 1 < nt) {
      stage(cb ^ 1, t + 1);   // overwrite of buf^1 is safe: its readers
                              // passed the end-of-iter-(t-1) barrier
      asm volatile("s_waitcnt vmcnt(8)" ::: "memory");  // retire tile t's 8
    } else {
      asm volatile("s_waitcnt vmcnt(0)" ::: "memory");
    }
    __builtin_amdgcn_s_barrier();              // tile t resident for all waves
    __builtin_amdgcn_sched_barrier(0);         // don't hoist ds_reads above
    const unsigned short* Ab = lds + cb * 16384;
    const unsigned short* Bb = Ab + 8192;
    bf16x8 af0[4], af1[4], bf0[4], bf1[4];
    #pragma unroll
    for (int i = 0; i < 4; ++i) {
      af0[i] = *(const bf16x8*)(Ab + rs_a + i * 1024 + cg0);
      af1[i] = *(const bf16x8*)(Ab + rs_a + i * 1024 + cg1);
      bf0[i] = *(const bf16x8*)(Bb + rs_b + i * 1024 + cg0);
      bf1[i] = *(const bf16x8*)(Bb + rs_b + i * 1024 + cg1);
    }
    #pragma unroll
    for (int i = 0; i < 4; ++i)
      #pragma unroll
      for (int j = 0; j < 4; ++j) {
        acc[i][j] = __builtin_amdgcn_mfma_f32_16x16x32_bf16(af0[i], bf0[j], acc[i][j], 0, 0, 0);
        acc[i][j] = __builtin_amdgcn_mfma_f32_16x16x32_bf16(af1[i], bf1[j], acc[i][j], 0, 0, 0);
      }
    asm volatile("s_waitcnt lgkmcnt(0)" ::: "memory");  // my reads retired
    __builtin_amdgcn_sched_barrier(0);
    __builtin_amdgcn_s_barrier();              // all waves done reading buf t
  }

  int isf32 = 0;
  if (EP == EP_RES2) isf32 = *flagp;
  const int qr = (lane >> 4) * 4;
  float bvs[4];
  #pragma unroll
  for (int tj = 0; tj < 4; ++tj) bvs[tj] = bf2f(bias[bn + wn + tj * 16 + fr]);
  #pragma unroll
  for (int ti = 0; ti < 4; ++ti) {
    #pragma unroll
    for (int r = 0; r < 4; ++r) {
      const int mr = bm + wm + ti * 16 + qr + r;
      size_t rowbase;
      if (EP == EP_WINRES) {
        int wi = mr / 49; int nt2 = mr - wi * 49;
        int bb = wi >> 4; int wb = wi & 15;
        int nh_i = wb >> 2; int nw_i = wb & 3;
        int hs = nt2 / 7; int wsx = nt2 - hs * 7;
        int l = nh_i * 196 + hs * 28 + nw_i * 7 + wsx;
        rowbase = ((size_t)bb * LL + l) * CC;
      } else if (EP == EP_RES2) {
        rowbase = (size_t)(mr + m_off) * N;
      } else {
        rowbase = (size_t)mr * N;
      }
      #pragma unroll
      for (int tj = 0; tj < 4; ++tj) {
        const int n = bn + wn + tj * 16 + fr;
        float v = acc[ti][tj][r] + bvs[tj];
        if (EP == EP_GELU) {
          // gelu(x) = x * sigmoid(1.59576912x + 0.07135482x^3)
          const float t2 = v * (1.5957691216f + 0.0713548162f * v * v);
          v = __fdividef(v, 1.0f + __expf(-t2));
          ((unsigned short*)outp)[rowbase + n] = f2bf(v);
        } else if (EP == EP_WINRES) {
          size_t idx = rowbase + n;
          v += bf2f(res[idx]);
          ((unsigned short*)outp)[idx] = f2bf(v);
        } else if (EP == EP_RES2) {
          size_t idx = rowbase + n;
          v += bf2f(res[idx]);
          if (isf32) ((float*)outp)[idx] = v;
          else       ((unsigned short*)outp)[idx] = f2bf(v);
        } else {
          ((unsigned short*)outp)[rowbase + n] = f2bf(v);
        }
      }
    }
  }
}

// ---------- MFMA windowed attention: one WAVE per (window, head) ----------
__global__ __launch_bounds__(64) void attn_mfma(
    const unsigned short* __restrict__ qkv, const float* __restrict__ bias_full,
    unsigned short* __restrict__ o, int wi_off) {
  __shared__ __align__(16) unsigned short Pl[64 * 72];
  __shared__ __align__(16) unsigned short vT[32 * 72];
  const int wi = blockIdx.x, h = blockIdx.y;
  const int lane = threadIdx.x;
  const int l15 = lane & 15;
  const int quad = lane >> 4;
  const unsigned short* base = qkv + (size_t)wi * NTOK * QKV_OUT + h * 96;

  bf16x8 qf[4], kf[4];
  #pragma unroll
  for (int i = 0; i < 4; ++i) {
    const int n = i * 16 + l15;
    if (n < NTOK) {
      const unsigned short* p = base + (size_t)n * QKV_OUT + quad * 8;
      qf[i] = *(const bf16x8*)(p);
      kf[i] = *(const bf16x8*)(p + 32);
    } else {
      qf[i] = (bf16x8)0; kf[i] = (bf16x8)0;
    }
  }

  for (int idx = lane; idx < 32 * 72; idx += 64) vT[idx] = 0;
  __syncthreads();
  for (int idx = lane; idx < NTOK * KD; idx += 64) {
    const int m = idx >> 5, d = idx & 31;
    vT[d * 72 + m] = base[(size_t)m * QKV_OUT + 64 + d];
  }

  f32x4 acc[4][4] = {};
  #pragma unroll
  for (int i = 0; i < 4; ++i)
    #pragma unroll
    for (int j = 0; j < 4; ++j)
      acc[i][j] = __builtin_amdgcn_mfma_f32_16x16x32_bf16(qf[i], kf[j], acc[i][j], 0, 0, 0);

  const float* bh = bias_full + h * NTOK * NTOK;
  float rinv[4][4];
  #pragma unroll
  for (int i = 0; i < 4; ++i) {
    #pragma unroll
    for (int r = 0; r < 4; ++r) {
      const int n = i * 16 + quad * 4 + r;
      float sv[4];
      #pragma unroll
      for (int j = 0; j < 4; ++j) {
        const int m = j * 16 + l15;
        float s = acc[i][j][r] * SCALE;
        if (n < NTOK && m < NTOK) s += bh[n * NTOK + m];
        if (m >= NTOK) s = -1e30f;
        sv[j] = s;
      }
      float mx = fmaxf(fmaxf(sv[0], sv[1]), fmaxf(sv[2], sv[3]));
      #pragma unroll
      for (int t = 1; t < 16; t <<= 1) mx = fmaxf(mx, __shfl_xor(mx, t));
      float sum = 0.f;
      #pragma unroll
      for (int j = 0; j < 4; ++j) {
        const float p = __expf(sv[j] - mx);
        sum += p;
        Pl[n * 72 + j * 16 + l15] = f2bf(p);
      }
      #pragma unroll
      for (int t = 1; t < 16; t <<= 1) sum += __shfl_xor(sum, t);
      rinv[i][r] = 1.f / sum;
    }
  }
  __syncthreads();

  f32x4 acc2[4][2] = {};
  #pragma unroll
  for (int kk = 0; kk < 2; ++kk) {
    bf16x8 pf[4], vf[2];
    #pragma unroll
    for (int i = 0; i < 4; ++i)
      pf[i] = *(const bf16x8*)(Pl + (i * 16 + l15) * 72 + kk * 32 + quad * 8);
    #pragma unroll
    for (int jd = 0; jd < 2; ++jd)
      vf[jd] = *(const bf16x8*)(vT + (jd * 16 + l15) * 72 + kk * 32 + quad * 8);
    #pragma unroll
    for (int i = 0; i < 4; ++i)
      #pragma unroll
      for (int jd = 0; jd < 2; ++jd)
        acc2[i][jd] = __builtin_amdgcn_mfma_f32_16x16x32_bf16(pf[i], vf[jd], acc2[i][jd], 0, 0, 0);
  }

  #pragma unroll
  for (int i = 0; i < 4; ++i) {
    #pragma unroll
    for (int r = 0; r < 4; ++r) {
      const int n = i * 16 + quad * 4 + r;
      if (n < NTOK) {
        const float ri = rinv[i][r];
        #pragma unroll
        for (int jd = 0; jd < 2; ++jd) {
          const int d = jd * 16 + l15;
          o[((size_t)(wi_off + wi) * NTOK + n) * CC + h * KD + d] = f2bf(acc2[i][jd][r] * ri);
        }
      }
    }
  }
}

// ---------- fused depthwise 3x3 conv + BN + LN_m ----------
__global__ __launch_bounds__(384) void conv_bn_ln(
    const unsigned short* __restrict__ x1, const unsigned short* __restrict__ cwT,
    const float* __restrict__ bnsc, const float* __restrict__ bnsh,
    const unsigned short* __restrict__ mg, const unsigned short* __restrict__ mb,
    unsigned short* __restrict__ x2, unsigned short* __restrict__ xm) {
  __shared__ float rs[8][48], rq[8][48];
  const int tid = threadIdx.x;
  const int pos = tid / 48;
  const int c8 = tid - pos * 48;
  const int c0 = c8 * 8;
  const int hw = blockIdx.x * 8 + pos;
  const int b = blockIdx.y;
  const int h = hw / 28, w = hw - h * 28;
  float acc[8] = {};
  #pragma unroll
  for (int t = 0; t < 9; ++t) {
    const int dh = t / 3 - 1, dw = t % 3 - 1;
    const int hh = h + dh, ww = w + dw;
    if (hh >= 0 && hh < 28 && ww >= 0 && ww < 28) {
      const uint4 xv = *(const uint4*)(x1 + ((size_t)b * LL + hh * 28 + ww) * CC + c0);
      const uint4 wv = *(const uint4*)(cwT + t * CC + c0);
      const unsigned short* xp = (const unsigned short*)&xv;
      const unsigned short* wp = (const unsigned short*)&wv;
      #pragma unroll
      for (int k = 0; k < 8; ++k) acc[k] += bf2f(xp[k]) * bf2f(wp[k]);
    }
  }
  const float4 sc0 = *(const float4*)(bnsc + c0);
  const float4 sc1 = *(const float4*)(bnsc + c0 + 4);
  const float4 sh0 = *(const float4*)(bnsh + c0);
  const float4 sh1 = *(const float4*)(bnsh + c0 + 4);
  float y[8];
  y[0] = acc[0] * sc0.x + sh0.x; y[1] = acc[1] * sc0.y + sh0.y;
  y[2] = acc[2] * sc0.z + sh0.z; y[3] = acc[3] * sc0.w + sh0.w;
  y[4] = acc[4] * sc1.x + sh1.x; y[5] = acc[5] * sc1.y + sh1.y;
  y[6] = acc[6] * sc1.z + sh1.z; y[7] = acc[7] * sc1.w + sh1.w;
  ushort4 pk0, pk1;
  pk0.x = f2bf(y[0]); pk0.y = f2bf(y[1]); pk0.z = f2bf(y[2]); pk0.w = f2bf(y[3]);
  pk1.x = f2bf(y[4]); pk1.y = f2bf(y[5]); pk1.z = f2bf(y[6]); pk1.w = f2bf(y[7]);
  const size_t row = ((size_t)b * LL + hw) * CC + c0;
  *(ushort4*)(x2 + row) = pk0;
  *(ushort4*)(x2 + row + 4) = pk1;
  float s = 0.f, q = 0.f;
  #pragma unroll
  for (int k = 0; k < 8; ++k) { s += y[k]; q += y[k] * y[k]; }
  rs[pos][c8] = s; rq[pos][c8] = q;
  __syncthreads();
  float tot = 0.f, tq = 0.f;
  #pragma unroll 8
  for (int i = 0; i < 48; ++i) { tot += rs[pos][i]; tq += rq[pos][i]; }
  const float mean = tot * (1.f / CC);
  const float var = tq * (1.f / CC) - mean * mean;
  const float inv = rsqrtf(var + EPS);
  const uint4 gv = *(const uint4*)(mg + c0);
  const uint4 bv = *(const uint4*)(mb + c0);
  const unsigned short* gp = (const unsigned short*)&gv;
  const unsigned short* bp = (const unsigned short*)&bv;
  ushort4 lo, hi;
  unsigned short outv[8];
  #pragma unroll
  for (int k = 0; k < 8; ++k)
    outv[k] = f2bf((y[k] - mean) * inv * bf2f(gp[k]) + bf2f(bp[k]));
  lo.x = outv[0]; lo.y = outv[1]; lo.z = outv[2]; lo.w = outv[3];
  hi.x = outv[4]; hi.y = outv[5]; hi.z = outv[6]; hi.w = outv[7];
  *(ushort4*)(xm + row) = lo;
  *(ushort4*)(xm + row + 4) = hi;
}

// ---------- launch ----------
extern "C" void kernel_launch(void* const* d_in, const int* in_sizes, int n_in,
                              void* d_out, int out_size, void* d_ws, size_t ws_size,
                              hipStream_t stream) {
  int* flag = (int*)d_ws;
  unsigned short* base = (unsigned short*)d_ws;

  CvtArgs args;
  size_t cur = 32;
  size_t off[19];
  for (int i = 0; i < 19; ++i) {
    off[i] = cur;
    args.src[i] = d_in[i];
    args.n[i] = (unsigned int)in_sizes[i];
    args.off[i] = (unsigned int)cur;
    cur += ((size_t)in_sizes[i] + 63) & ~(size_t)63;
  }
  const unsigned short* cx   = base + off[0];
  const unsigned short* cgA  = base + off[1];
  const unsigned short* cbA  = base + off[2];
  const unsigned short* cQw  = base + off[3];
  const unsigned short* cQb  = base + off[4];
  const unsigned short* cAb  = base + off[5];
  const unsigned short* cPw  = base + off[6];
  const unsigned short* cPb  = base + off[7];
  const unsigned short* cCw  = base + off[8];
  const unsigned short* cBg  = base + off[9];
  const unsigned short* cBb  = base + off[10];
  const unsigned short* cBm  = base + off[11];
  const unsigned short* cBv  = base + off[12];
  const unsigned short* cMg  = base + off[13];
  const unsigned short* cMb  = base + off[14];
  const unsigned short* cF1w = base + off[15];
  const unsigned short* cF1b = base + off[16];
  const unsigned short* cF2w = base + off[17];
  const unsigned short* cF2b = base + off[18];
  const int* bias_idxs = (const int*)d_in[19];

  const size_t SZ = (size_t)MTOT * CC;             // 19267584 elems
  // chunking: merge M-halves into one launch if workspace permits.
  const size_t need_full_bytes =
      (cur + SZ + (size_t)MTOT * HID) * 2 + 512 * 1024;
  const int nchunk = (ws_size >= need_full_bytes) ? 1 : 2;
  const int MC = MTOT / nchunk;                    // GEMM rows per chunk
  const int WC = 1024 / nchunk;                    // windows per chunk
  const size_t buf2_cap = (size_t)MC * HID;

  unsigned short* o_buf = base + cur;               // attn out o; later xm
  unsigned short* buf2  = o_buf + SZ;               // qkv chunk / h chunk
  unsigned short* x2    = base + off[0];            // conv+BN out overwrites spent cx
  float* bias_full = (float*)(buf2 + buf2_cap);     // [12][49][49] f32
  unsigned short* cwT = (unsigned short*)(bias_full + 12 * NTOK * NTOK);  // [9][384] bf16
  float* bnsc = (float*)(cwT + 9 * CC);
  float* bnsh = bnsc + CC;

  unsigned short* xn = (unsigned short*)d_out;

  // 0. dtype detect + canonicalize + tables
  detect_kernel<<<1, 256, 0, stream>>>((const unsigned short*)d_in[0], flag);
  convert_kernel<<<dim3(512, 19), 256, 0, stream>>>(args, base, flag);
  bias_kernel<<<NHEAD, 256, 0, stream>>>(cAb, bias_idxs, bias_full);
  prep_kernel<<<1, 384, 0, stream>>>(cCw, cBg, cBb, cBm, cBv, cwT, bnsc, bnsh);

  // 1. window partition + LN_a -> xn (d_out)
  ln_kernel<<<dim3(49, 1024), 128, 0, stream>>>(cx, cgA, cbA, xn);

  // 2+3. qkv projection + MFMA attention
  for (int c = 0; c < nchunk; ++c) {
    gemm128<EP_PLAIN><<<(MC / 128) * (QKV_OUT / 128), 256, 0, stream>>>(
        xn + (size_t)c * MC * CC, cQw, cQb, nullptr, buf2, CC, QKV_OUT, 0, nullptr,
        QKV_OUT / 128);
    attn_mfma<<<dim3(WC, NHEAD), 64, 0, stream>>>(buf2, bias_full, o_buf, c * WC);
  }

  // 4. proj + un-window + residual(x) -> x1 (d_out)
  gemm128<EP_WINRES><<<(MTOT / 128) * (CC / 128), 256, 0, stream>>>(
      o_buf, cPw, cPb, cx, d_out, CC, CC, 0, nullptr, CC / 128);

  // 5. fused conv + BN + LN_m -> x2 (residual) and xm (o_buf, fc1 input)
  conv_bn_ln<<<dim3(98, BATCH), 384, 0, stream>>>(
      (const unsigned short*)d_out, cwT, bnsc, bnsh, cMg, cMb, x2, o_buf);

  // 6+7. MLP; fc2 writes final output
  for (int c = 0; c < nchunk; ++c) {
    gemm128<EP_GELU><<<(MC / 128) * (HID / 128), 256, 0, stream>>>(
        o_buf + (size_t)c * MC * CC, cF1w, cF1b, nullptr, buf2, CC, HID, 0, nullptr,
        HID / 128);
    gemm128<EP_RES2><<<(MC / 128) * (CC / 128), 256, 0, stream>>>(
        buf2, cF2w, cF2b, x2, d_out, HID, CC, c * MC, flag, CC / 128);
  }
}

// Round 5
// 670.002 us; speedup vs baseline: 1.1492x; 1.0579x over previous
//
#include <hip/hip_runtime.h>
#include <hip/hip_bf16.h>
#include <stdint.h>

// ---------- constants ----------
#define BATCH 64
#define CC 384
#define NHEAD 12
#define KD 32
#define NTOK 49
#define LL 784
#define MTOT 50176        // BATCH*LL = 1024 windows * 49
#define HID 1536
#define QKV_OUT 1152
#define SCALE 0.17677669529663687f
#define EPS 1e-5f

typedef __bf16 bf16x8 __attribute__((ext_vector_type(8)));
typedef float f32x4 __attribute__((ext_vector_type(4)));

__device__ __forceinline__ float bf2f(unsigned short u) {
  union { unsigned int u; float f; } cv; cv.u = ((unsigned int)u) << 16; return cv.f;
}
__device__ __forceinline__ unsigned short f2bf(float f) {
  union { float f; unsigned int u; } cv; cv.f = f;
  unsigned int r = cv.u + 0x7FFFu + ((cv.u >> 16) & 1u);
  return (unsigned short)(r >> 16);
}
__device__ __forceinline__ void gl_lds16(const unsigned short* g, unsigned short* l) {
  __builtin_amdgcn_global_load_lds(
      (const __attribute__((address_space(1))) unsigned int*)g,
      (__attribute__((address_space(3))) unsigned int*)l, 16, 0, 0);
}

// ---------- dtype detection (bf16 vs fp32 wire format) ----------
__global__ void detect_kernel(const unsigned short* __restrict__ x, int* flag) {
  __shared__ int cnt;
  if (threadIdx.x == 0) cnt = 0;
  __syncthreads();
  int c = 0;
  for (int i = threadIdx.x; i < 4096; i += 256) {
    if (((x[i] >> 7) & 0xFF) == 0xFF) c++;
  }
  atomicAdd(&cnt, c);
  __syncthreads();
  if (threadIdx.x == 0) *flag = (cnt > 0) ? 1 : 0;
}

// ---------- input canonicalization (vectorized) ----------
struct CvtArgs {
  const void* src[19];
  unsigned int n[19];
  unsigned int off[19];
};
__global__ __launch_bounds__(256) void convert_kernel(
    CvtArgs a, unsigned short* __restrict__ dst, const int* __restrict__ flag) {
  const int which = blockIdx.y;
  const unsigned int nn = a.n[which];
  unsigned short* d = dst + a.off[which];
  const unsigned int stride = gridDim.x * blockDim.x;
  const unsigned int idx = blockIdx.x * blockDim.x + threadIdx.x;
  const unsigned int ng = nn >> 3;
  if (*flag) {
    const float* s = (const float*)a.src[which];
    for (unsigned int g = idx; g < ng; g += stride) {
      const float4 f0 = ((const float4*)s)[g * 2];
      const float4 f1 = ((const float4*)s)[g * 2 + 1];
      ushort4 lo, hi;
      lo.x = f2bf(f0.x); lo.y = f2bf(f0.y); lo.z = f2bf(f0.z); lo.w = f2bf(f0.w);
      hi.x = f2bf(f1.x); hi.y = f2bf(f1.y); hi.z = f2bf(f1.z); hi.w = f2bf(f1.w);
      ((ushort4*)d)[g * 2] = lo;
      ((ushort4*)d)[g * 2 + 1] = hi;
    }
    for (unsigned int i = ng * 8 + idx; i < nn; i += stride) d[i] = f2bf(s[i]);
  } else {
    const unsigned short* s = (const unsigned short*)a.src[which];
    for (unsigned int g = idx; g < ng; g += stride)
      ((uint4*)d)[g] = ((const uint4*)s)[g];
    for (unsigned int i = ng * 8 + idx; i < nn; i += stride) d[i] = s[i];
  }
}

// ---------- bias table precompute: bias_full[h][n][m] fp32 ----------
__global__ __launch_bounds__(256) void bias_kernel(
    const unsigned short* __restrict__ cAb, const int* __restrict__ bias_idxs,
    float* __restrict__ bias_full) {
  const int h = blockIdx.x;
  for (int i = threadIdx.x; i < NTOK * NTOK; i += 256)
    bias_full[h * NTOK * NTOK + i] = bf2f(cAb[h * NTOK + bias_idxs[i]]);
}

// ---------- conv/BN table precompute: cwT[t][c] bf16, bn scale/shift fp32 ----------
__global__ __launch_bounds__(384) void prep_kernel(
    const unsigned short* __restrict__ cw, const unsigned short* __restrict__ bg,
    const unsigned short* __restrict__ bb, const unsigned short* __restrict__ bm,
    const unsigned short* __restrict__ bv,
    unsigned short* __restrict__ cwT, float* __restrict__ bnsc, float* __restrict__ bnsh) {
  const int c = threadIdx.x;
  const float sc = bf2f(bg[c]) * rsqrtf(bf2f(bv[c]) + EPS);
  bnsc[c] = sc;
  bnsh[c] = bf2f(bb[c]) - bf2f(bm[c]) * sc;
  #pragma unroll
  for (int t = 0; t < 9; ++t) cwT[t * CC + c] = cw[c * 9 + t];
}

// ---------- LayerNorm + window gather (pre-attention) ----------
__global__ __launch_bounds__(128) void ln_kernel(
    const unsigned short* __restrict__ x, const unsigned short* __restrict__ g,
    const unsigned short* __restrict__ b, unsigned short* __restrict__ out) {
  const int tid = threadIdx.x;
  int wi = blockIdx.y, n = blockIdx.x;
  int bb = wi >> 4, wb = wi & 15;
  int nh_i = wb >> 2, nw_i = wb & 3;
  int hs = n / 7, wsx = n - hs * 7;
  int l = nh_i * 196 + hs * 28 + nw_i * 7 + wsx;
  size_t src_row = (size_t)bb * LL + l;
  size_t dst_row = (size_t)wi * NTOK + n;
  const unsigned short* xr = x + src_row * CC;
  float vals[3]; float s = 0.f, sq = 0.f;
  for (int j = 0; j < 3; ++j) {
    vals[j] = bf2f(xr[tid + 128 * j]);
    s += vals[j]; sq += vals[j] * vals[j];
  }
  for (int off = 32; off; off >>= 1) { s += __shfl_xor(s, off); sq += __shfl_xor(sq, off); }
  __shared__ float red[4];
  const int wv = tid >> 6;
  if ((tid & 63) == 0) { red[wv] = s; red[2 + wv] = sq; }
  __syncthreads();
  float tot = red[0] + red[1], totq = red[2] + red[3];
  float mean = tot * (1.f / CC);
  float var = totq * (1.f / CC) - mean * mean;
  float inv = rsqrtf(var + EPS);
  unsigned short* orow = out + dst_row * CC;
  for (int j = 0; j < 3; ++j) {
    int c = tid + 128 * j;
    float y = (vals[j] - mean) * inv * bf2f(g[c]) + bf2f(b[c]);
    orow[c] = f2bf(y);
  }
}

// ---------- GEMM: 128x128 tile, 4 waves, 4x4 acc, BK=32 ----------
// K-loop: 3 LDS buffers (48 KB -> 3 blocks/CU, 12 waves: the round-2
// occupancy point), prefetch depth 2, counted s_waitcnt vmcnt(8/4/0) (T4).
// [R4 lesson = m132: BK=64 dbuf (64 KB) capped 2 blocks/CU and regressed.]
// T2 swizzle (both-sides, rule #21): stage reads global granule
// (c ^ (row&3))*8 into linear LDS; reader uses granule (quad ^ (fr&3)).
// 8-way -> 4-way read conflict at zero instruction cost.
// Grid: 1D, XCD-chunked bijective remap (m204) + N-fastest tile order so
// blocks sharing an A-panel land consecutively on one XCD (R4: fc2 FETCH
// 269 -> 117 MB; keep).
enum { EP_PLAIN = 0, EP_GELU = 1, EP_WINRES = 2, EP_RES2 = 3 };

template <int EP>
__global__ __launch_bounds__(256) void gemm128(
    const unsigned short* __restrict__ A, const unsigned short* __restrict__ W,
    const unsigned short* __restrict__ bias, const unsigned short* __restrict__ res,
    void* __restrict__ outp, int K, int N, int m_off, const int* __restrict__ flagp,
    int Nt) {
  __shared__ __align__(16) unsigned short lds[3 * 8192];  // 3 x (A 128x32 + B 128x32)
  const int tid = threadIdx.x;
  const int lane = tid & 63;
  const int wave = tid >> 6;
  // --- XCD-chunked bijective remap (m204), then N-fastest tile order ---
  const int nwg = gridDim.x;
  const int id = blockIdx.x;
  const int q8 = nwg >> 3, r8 = nwg & 7;
  const int xcd = id & 7, rank = id >> 3;
  const int wgid = (xcd < r8 ? xcd * (q8 + 1) : r8 * (q8 + 1) + (xcd - r8) * q8) + rank;
  const int bm = (wgid / Nt) * 128;
  const int bn = (wgid - (wgid / Nt) * Nt) * 128;
  const int wm = (wave >> 1) * 64;
  const int wn = (wave & 1) * 64;
  // staging: row = tid>>2 (0..63, +64 for second half), granule c = tid&3.
  // source col XOR-swizzled; LDS dest linear (tid*8).
  const int srow = tid >> 2;
  const int s_col = ((tid & 3) ^ (srow & 3)) * 8;   // swizzled source col
  const unsigned short* Ap0 = A + (size_t)(bm + srow) * K + s_col;
  const unsigned short* Wp0 = W + (size_t)(bn + srow) * K + s_col;
  const size_t rstep = (size_t)64 * K;
  f32x4 acc[4][4] = {};
  const int fr = lane & 15;
  const int quad = lane >> 4;
  const int nt = K >> 5;   // K % 32 == 0 (384, 1536)
  const int cg = (quad ^ (fr & 3)) * 8;   // swizzled read granule

  auto stage = [&](int bsel, int t) {
    const unsigned short* ap = Ap0 + (size_t)t * 32;
    const unsigned short* wp = Wp0 + (size_t)t * 32;
    unsigned short* al = lds + bsel * 8192 + tid * 8;
    unsigned short* bl = al + 4096;
    gl_lds16(ap, al);
    gl_lds16(ap + rstep, al + 2048);
    gl_lds16(wp, bl);
    gl_lds16(wp + rstep, bl + 2048);
  };

  // prologue: tiles 0 and 1 in flight (8 outstanding loads per thread)
  stage(0, 0);
  stage(1, 1);
  int b = 0;
  for (int t = 0; t < nt; ++t) {
    if (t + 2 < nt) stage(b ? b - 1 : 2, t + 2);   // buf[(t+2)%3] == buf[(t-1)%3]
    // retire exactly tile t's 4 loads; keep tiles t+1,t+2 in flight
    if (t + 3 <= nt)      asm volatile("s_waitcnt vmcnt(8)" ::: "memory");
    else if (t + 2 == nt) asm volatile("s_waitcnt vmcnt(4)" ::: "memory");
    else                  asm volatile("s_waitcnt vmcnt(0)" ::: "memory");
    __builtin_amdgcn_s_barrier();              // tile t resident for all waves
    __builtin_amdgcn_sched_barrier(0);         // don't hoist ds_reads above
    const unsigned short* Ab = lds + b * 8192;
    const unsigned short* Bb = Ab + 4096;
    bf16x8 af[4], bfr[4];
    #pragma unroll
    for (int i = 0; i < 4; ++i) {
      af[i]  = *(const bf16x8*)(Ab + (wm + i * 16 + fr) * 32 + cg);
      bfr[i] = *(const bf16x8*)(Bb + (wn + i * 16 + fr) * 32 + cg);
    }
    #pragma unroll
    for (int i = 0; i < 4; ++i)
      #pragma unroll
      for (int j = 0; j < 4; ++j)
        acc[i][j] = __builtin_amdgcn_mfma_f32_16x16x32_bf16(af[i], bfr[j], acc[i][j], 0, 0, 0);
    asm volatile("s_waitcnt lgkmcnt(0)" ::: "memory");  // my reads retired
    __builtin_amdgcn_sched_barrier(0);
    __builtin_amdgcn_s_barrier();              // all waves done reading buf t
    b = (b == 2) ? 0 : b + 1;
  }

  int isf32 = 0;
  if (EP == EP_RES2) isf32 = *flagp;
  const int qr = (lane >> 4) * 4;
  float bvs[4];
  #pragma unroll
  for (int tj = 0; tj < 4; ++tj) bvs[tj] = bf2f(bias[bn + wn + tj * 16 + fr]);
  #pragma unroll
  for (int ti = 0; ti < 4; ++ti) {
    #pragma unroll
    for (int r = 0; r < 4; ++r) {
      const int mr = bm + wm + ti * 16 + qr + r;
      size_t rowbase;
      if (EP == EP_WINRES) {
        int wi = mr / 49; int nt2 = mr - wi * 49;
        int bb = wi >> 4; int wb = wi & 15;
        int nh_i = wb >> 2; int nw_i = wb & 3;
        int hs = nt2 / 7; int wsx = nt2 - hs * 7;
        int l = nh_i * 196 + hs * 28 + nw_i * 7 + wsx;
        rowbase = ((size_t)bb * LL + l) * CC;
      } else if (EP == EP_RES2) {
        rowbase = (size_t)(mr + m_off) * N;
      } else {
        rowbase = (size_t)mr * N;
      }
      #pragma unroll
      for (int tj = 0; tj < 4; ++tj) {
        const int n = bn + wn + tj * 16 + fr;
        float v = acc[ti][tj][r] + bvs[tj];
        if (EP == EP_GELU) {
          // gelu(x) = x * sigmoid(1.59576912x + 0.07135482x^3)
          const float t2 = v * (1.5957691216f + 0.0713548162f * v * v);
          v = __fdividef(v, 1.0f + __expf(-t2));
          ((unsigned short*)outp)[rowbase + n] = f2bf(v);
        } else if (EP == EP_WINRES) {
          size_t idx = rowbase + n;
          v += bf2f(res[idx]);
          ((unsigned short*)outp)[idx] = f2bf(v);
        } else if (EP == EP_RES2) {
          size_t idx = rowbase + n;
          v += bf2f(res[idx]);
          if (isf32) ((float*)outp)[idx] = v;
          else       ((unsigned short*)outp)[idx] = f2bf(v);
        } else {
          ((unsigned short*)outp)[rowbase + n] = f2bf(v);
        }
      }
    }
  }
}

// ---------- MFMA windowed attention: one WAVE per (window, head) ----------
__global__ __launch_bounds__(64) void attn_mfma(
    const unsigned short* __restrict__ qkv, const float* __restrict__ bias_full,
    unsigned short* __restrict__ o, int wi_off) {
  __shared__ __align__(16) unsigned short Pl[64 * 72];
  __shared__ __align__(16) unsigned short vT[32 * 72];
  const int wi = blockIdx.x, h = blockIdx.y;
  const int lane = threadIdx.x;
  const int l15 = lane & 15;
  const int quad = lane >> 4;
  const unsigned short* base = qkv + (size_t)wi * NTOK * QKV_OUT + h * 96;

  bf16x8 qf[4], kf[4];
  #pragma unroll
  for (int i = 0; i < 4; ++i) {
    const int n = i * 16 + l15;
    if (n < NTOK) {
      const unsigned short* p = base + (size_t)n * QKV_OUT + quad * 8;
      qf[i] = *(const bf16x8*)(p);
      kf[i] = *(const bf16x8*)(p + 32);
    } else {
      qf[i] = (bf16x8)0; kf[i] = (bf16x8)0;
    }
  }

  for (int idx = lane; idx < 32 * 72; idx += 64) vT[idx] = 0;
  __syncthreads();
  for (int idx = lane; idx < NTOK * KD; idx += 64) {
    const int m = idx >> 5, d = idx & 31;
    vT[d * 72 + m] = base[(size_t)m * QKV_OUT + 64 + d];
  }

  f32x4 acc[4][4] = {};
  #pragma unroll
  for (int i = 0; i < 4; ++i)
    #pragma unroll
    for (int j = 0; j < 4; ++j)
      acc[i][j] = __builtin_amdgcn_mfma_f32_16x16x32_bf16(qf[i], kf[j], acc[i][j], 0, 0, 0);

  const float* bh = bias_full + h * NTOK * NTOK;
  float rinv[4][4];
  #pragma unroll
  for (int i = 0; i < 4; ++i) {
    #pragma unroll
    for (int r = 0; r < 4; ++r) {
      const int n = i * 16 + quad * 4 + r;
      float sv[4];
      #pragma unroll
      for (int j = 0; j < 4; ++j) {
        const int m = j * 16 + l15;
        float s = acc[i][j][r] * SCALE;
        if (n < NTOK && m < NTOK) s += bh[n * NTOK + m];
        if (m >= NTOK) s = -1e30f;
        sv[j] = s;
      }
      float mx = fmaxf(fmaxf(sv[0], sv[1]), fmaxf(sv[2], sv[3]));
      #pragma unroll
      for (int t = 1; t < 16; t <<= 1) mx = fmaxf(mx, __shfl_xor(mx, t));
      float sum = 0.f;
      #pragma unroll
      for (int j = 0; j < 4; ++j) {
        const float p = __expf(sv[j] - mx);
        sum += p;
        Pl[n * 72 + j * 16 + l15] = f2bf(p);
      }
      #pragma unroll
      for (int t = 1; t < 16; t <<= 1) sum += __shfl_xor(sum, t);
      rinv[i][r] = 1.f / sum;
    }
  }
  __syncthreads();

  f32x4 acc2[4][2] = {};
  #pragma unroll
  for (int kk = 0; kk < 2; ++kk) {
    bf16x8 pf[4], vf[2];
    #pragma unroll
    for (int i = 0; i < 4; ++i)
      pf[i] = *(const bf16x8*)(Pl + (i * 16 + l15) * 72 + kk * 32 + quad * 8);
    #pragma unroll
    for (int jd = 0; jd < 2; ++jd)
      vf[jd] = *(const bf16x8*)(vT + (jd * 16 + l15) * 72 + kk * 32 + quad * 8);
    #pragma unroll
    for (int i = 0; i < 4; ++i)
      #pragma unroll
      for (int jd = 0; jd < 2; ++jd)
        acc2[i][jd] = __builtin_amdgcn_mfma_f32_16x16x32_bf16(pf[i], vf[jd], acc2[i][jd], 0, 0, 0);
  }

  #pragma unroll
  for (int i = 0; i < 4; ++i) {
    #pragma unroll
    for (int r = 0; r < 4; ++r) {
      const int n = i * 16 + quad * 4 + r;
      if (n < NTOK) {
        const float ri = rinv[i][r];
        #pragma unroll
        for (int jd = 0; jd < 2; ++jd) {
          const int d = jd * 16 + l15;
          o[((size_t)(wi_off + wi) * NTOK + n) * CC + h * KD + d] = f2bf(acc2[i][jd][r] * ri);
        }
      }
    }
  }
}

// ---------- fused depthwise 3x3 conv + BN + LN_m ----------
__global__ __launch_bounds__(384) void conv_bn_ln(
    const unsigned short* __restrict__ x1, const unsigned short* __restrict__ cwT,
    const float* __restrict__ bnsc, const float* __restrict__ bnsh,
    const unsigned short* __restrict__ mg, const unsigned short* __restrict__ mb,
    unsigned short* __restrict__ x2, unsigned short* __restrict__ xm) {
  __shared__ float rs[8][48], rq[8][48];
  const int tid = threadIdx.x;
  const int pos = tid / 48;
  const int c8 = tid - pos * 48;
  const int c0 = c8 * 8;
  const int hw = blockIdx.x * 8 + pos;
  const int b = blockIdx.y;
  const int h = hw / 28, w = hw - h * 28;
  float acc[8] = {};
  #pragma unroll
  for (int t = 0; t < 9; ++t) {
    const int dh = t / 3 - 1, dw = t % 3 - 1;
    const int hh = h + dh, ww = w + dw;
    if (hh >= 0 && hh < 28 && ww >= 0 && ww < 28) {
      const uint4 xv = *(const uint4*)(x1 + ((size_t)b * LL + hh * 28 + ww) * CC + c0);
      const uint4 wv = *(const uint4*)(cwT + t * CC + c0);
      const unsigned short* xp = (const unsigned short*)&xv;
      const unsigned short* wp = (const unsigned short*)&wv;
      #pragma unroll
      for (int k = 0; k < 8; ++k) acc[k] += bf2f(xp[k]) * bf2f(wp[k]);
    }
  }
  const float4 sc0 = *(const float4*)(bnsc + c0);
  const float4 sc1 = *(const float4*)(bnsc + c0 + 4);
  const float4 sh0 = *(const float4*)(bnsh + c0);
  const float4 sh1 = *(const float4*)(bnsh + c0 + 4);
  float y[8];
  y[0] = acc[0] * sc0.x + sh0.x; y[1] = acc[1] * sc0.y + sh0.y;
  y[2] = acc[2] * sc0.z + sh0.z; y[3] = acc[3] * sc0.w + sh0.w;
  y[4] = acc[4] * sc1.x + sh1.x; y[5] = acc[5] * sc1.y + sh1.y;
  y[6] = acc[6] * sc1.z + sh1.z; y[7] = acc[7] * sc1.w + sh1.w;
  ushort4 pk0, pk1;
  pk0.x = f2bf(y[0]); pk0.y = f2bf(y[1]); pk0.z = f2bf(y[2]); pk0.w = f2bf(y[3]);
  pk1.x = f2bf(y[4]); pk1.y = f2bf(y[5]); pk1.z = f2bf(y[6]); pk1.w = f2bf(y[7]);
  const size_t row = ((size_t)b * LL + hw) * CC + c0;
  *(ushort4*)(x2 + row) = pk0;
  *(ushort4*)(x2 + row + 4) = pk1;
  float s = 0.f, q = 0.f;
  #pragma unroll
  for (int k = 0; k < 8; ++k) { s += y[k]; q += y[k] * y[k]; }
  rs[pos][c8] = s; rq[pos][c8] = q;
  __syncthreads();
  float tot = 0.f, tq = 0.f;
  #pragma unroll 8
  for (int i = 0; i < 48; ++i) { tot += rs[pos][i]; tq += rq[pos][i]; }
  const float mean = tot * (1.f / CC);
  const float var = tq * (1.f / CC) - mean * mean;
  const float inv = rsqrtf(var + EPS);
  const uint4 gv = *(const uint4*)(mg + c0);
  const uint4 bv = *(const uint4*)(mb + c0);
  const unsigned short* gp = (const unsigned short*)&gv;
  const unsigned short* bp = (const unsigned short*)&bv;
  ushort4 lo, hi;
  unsigned short outv[8];
  #pragma unroll
  for (int k = 0; k < 8; ++k)
    outv[k] = f2bf((y[k] - mean) * inv * bf2f(gp[k]) + bf2f(bp[k]));
  lo.x = outv[0]; lo.y = outv[1]; lo.z = outv[2]; lo.w = outv[3];
  hi.x = outv[4]; hi.y = outv[5]; hi.z = outv[6]; hi.w = outv[7];
  *(ushort4*)(xm + row) = lo;
  *(ushort4*)(xm + row + 4) = hi;
}

// ---------- launch ----------
extern "C" void kernel_launch(void* const* d_in, const int* in_sizes, int n_in,
                              void* d_out, int out_size, void* d_ws, size_t ws_size,
                              hipStream_t stream) {
  int* flag = (int*)d_ws;
  unsigned short* base = (unsigned short*)d_ws;

  CvtArgs args;
  size_t cur = 32;
  size_t off[19];
  for (int i = 0; i < 19; ++i) {
    off[i] = cur;
    args.src[i] = d_in[i];
    args.n[i] = (unsigned int)in_sizes[i];
    args.off[i] = (unsigned int)cur;
    cur += ((size_t)in_sizes[i] + 63) & ~(size_t)63;
  }
  const unsigned short* cx   = base + off[0];
  const unsigned short* cgA  = base + off[1];
  const unsigned short* cbA  = base + off[2];
  const unsigned short* cQw  = base + off[3];
  const unsigned short* cQb  = base + off[4];
  const unsigned short* cAb  = base + off[5];
  const unsigned short* cPw  = base + off[6];
  const unsigned short* cPb  = base + off[7];
  const unsigned short* cCw  = base + off[8];
  const unsigned short* cBg  = base + off[9];
  const unsigned short* cBb  = base + off[10];
  const unsigned short* cBm  = base + off[11];
  const unsigned short* cBv  = base + off[12];
  const unsigned short* cMg  = base + off[13];
  const unsigned short* cMb  = base + off[14];
  const unsigned short* cF1w = base + off[15];
  const unsigned short* cF1b = base + off[16];
  const unsigned short* cF2w = base + off[17];
  const unsigned short* cF2b = base + off[18];
  const int* bias_idxs = (const int*)d_in[19];

  const size_t SZ = (size_t)MTOT * CC;             // 19267584 elems
  // chunking: merge M-halves into one launch if workspace permits.
  const size_t need_full_bytes =
      (cur + SZ + (size_t)MTOT * HID) * 2 + 512 * 1024;
  const int nchunk = (ws_size >= need_full_bytes) ? 1 : 2;
  const int MC = MTOT / nchunk;                    // GEMM rows per chunk
  const int WC = 1024 / nchunk;                    // windows per chunk
  const size_t buf2_cap = (size_t)MC * HID;

  unsigned short* o_buf = base + cur;               // attn out o; later xm
  unsigned short* buf2  = o_buf + SZ;               // qkv chunk / h chunk
  unsigned short* x2    = base + off[0];            // conv+BN out overwrites spent cx
  float* bias_full = (float*)(buf2 + buf2_cap);     // [12][49][49] f32
  unsigned short* cwT = (unsigned short*)(bias_full + 12 * NTOK * NTOK);  // [9][384] bf16
  float* bnsc = (float*)(cwT + 9 * CC);
  float* bnsh = bnsc + CC;

  unsigned short* xn = (unsigned short*)d_out;

  // 0. dtype detect + canonicalize + tables
  detect_kernel<<<1, 256, 0, stream>>>((const unsigned short*)d_in[0], flag);
  convert_kernel<<<dim3(512, 19), 256, 0, stream>>>(args, base, flag);
  bias_kernel<<<NHEAD, 256, 0, stream>>>(cAb, bias_idxs, bias_full);
  prep_kernel<<<1, 384, 0, stream>>>(cCw, cBg, cBb, cBm, cBv, cwT, bnsc, bnsh);

  // 1. window partition + LN_a -> xn (d_out)
  ln_kernel<<<dim3(49, 1024), 128, 0, stream>>>(cx, cgA, cbA, xn);

  // 2+3. qkv projection + MFMA attention
  for (int c = 0; c < nchunk; ++c) {
    gemm128<EP_PLAIN><<<(MC / 128) * (QKV_OUT / 128), 256, 0, stream>>>(
        xn + (size_t)c * MC * CC, cQw, cQb, nullptr, buf2, CC, QKV_OUT, 0, nullptr,
        QKV_OUT / 128);
    attn_mfma<<<dim3(WC, NHEAD), 64, 0, stream>>>(buf2, bias_full, o_buf, c * WC);
  }

  // 4. proj + un-window + residual(x) -> x1 (d_out)
  gemm128<EP_WINRES><<<(MTOT / 128) * (CC / 128), 256, 0, stream>>>(
      o_buf, cPw, cPb, cx, d_out, CC, CC, 0, nullptr, CC / 128);

  // 5. fused conv + BN + LN_m -> x2 (residual) and xm (o_buf, fc1 input)
  conv_bn_ln<<<dim3(98, BATCH), 384, 0, stream>>>(
      (const unsigned short*)d_out, cwT, bnsc, bnsh, cMg, cMb, x2, o_buf);

  // 6+7. MLP; fc2 writes final output
  for (int c = 0; c < nchunk; ++c) {
    gemm128<EP_GELU><<<(MC / 128) * (HID / 128), 256, 0, stream>>>(
        o_buf + (size_t)c * MC * CC, cF1w, cF1b, nullptr, buf2, CC, HID, 0, nullptr,
        HID / 128);
    gemm128<EP_RES2><<<(MC / 128) * (CC / 128), 256, 0, stream>>>(
        buf2, cF2w, cF2b, x2, d_out, HID, CC, c * MC, flag, CC / 128);
  }
}

// Round 6
// 657.602 us; speedup vs baseline: 1.1708x; 1.0189x over previous
//
#include <hip/hip_runtime.h>
#include <hip/hip_bf16.h>
#include <stdint.h>

// ---------- constants ----------
#define BATCH 64
#define CC 384
#define NHEAD 12
#define KD 32
#define NTOK 49
#define LL 784
#define MTOT 50176        // BATCH*LL = 1024 windows * 49
#define HID 1536
#define QKV_OUT 1152
#define SCALE 0.17677669529663687f
#define EPS 1e-5f

typedef __bf16 bf16x8 __attribute__((ext_vector_type(8)));
typedef float f32x4 __attribute__((ext_vector_type(4)));

__device__ __forceinline__ float bf2f(unsigned short u) {
  union { unsigned int u; float f; } cv; cv.u = ((unsigned int)u) << 16; return cv.f;
}
__device__ __forceinline__ unsigned short f2bf(float f) {
  union { float f; unsigned int u; } cv; cv.f = f;
  unsigned int r = cv.u + 0x7FFFu + ((cv.u >> 16) & 1u);
  return (unsigned short)(r >> 16);
}
__device__ __forceinline__ void gl_lds16(const unsigned short* g, unsigned short* l) {
  __builtin_amdgcn_global_load_lds(
      (const __attribute__((address_space(1))) unsigned int*)g,
      (__attribute__((address_space(3))) unsigned int*)l, 16, 0, 0);
}

// ---------- dtype detection (bf16 vs fp32 wire format) ----------
__global__ void detect_kernel(const unsigned short* __restrict__ x, int* flag) {
  __shared__ int cnt;
  if (threadIdx.x == 0) cnt = 0;
  __syncthreads();
  int c = 0;
  for (int i = threadIdx.x; i < 4096; i += 256) {
    if (((x[i] >> 7) & 0xFF) == 0xFF) c++;
  }
  atomicAdd(&cnt, c);
  __syncthreads();
  if (threadIdx.x == 0) *flag = (cnt > 0) ? 1 : 0;
}

// ---------- input canonicalization (vectorized) ----------
struct CvtArgs {
  const void* src[19];
  unsigned int n[19];
  unsigned int off[19];
};
__global__ __launch_bounds__(256) void convert_kernel(
    CvtArgs a, unsigned short* __restrict__ dst, const int* __restrict__ flag) {
  const int which = blockIdx.y;
  const unsigned int nn = a.n[which];
  unsigned short* d = dst + a.off[which];
  const unsigned int stride = gridDim.x * blockDim.x;
  const unsigned int idx = blockIdx.x * blockDim.x + threadIdx.x;
  const unsigned int ng = nn >> 3;
  if (*flag) {
    const float* s = (const float*)a.src[which];
    for (unsigned int g = idx; g < ng; g += stride) {
      const float4 f0 = ((const float4*)s)[g * 2];
      const float4 f1 = ((const float4*)s)[g * 2 + 1];
      ushort4 lo, hi;
      lo.x = f2bf(f0.x); lo.y = f2bf(f0.y); lo.z = f2bf(f0.z); lo.w = f2bf(f0.w);
      hi.x = f2bf(f1.x); hi.y = f2bf(f1.y); hi.z = f2bf(f1.z); hi.w = f2bf(f1.w);
      ((ushort4*)d)[g * 2] = lo;
      ((ushort4*)d)[g * 2 + 1] = hi;
    }
    for (unsigned int i = ng * 8 + idx; i < nn; i += stride) d[i] = f2bf(s[i]);
  } else {
    const unsigned short* s = (const unsigned short*)a.src[which];
    for (unsigned int g = idx; g < ng; g += stride)
      ((uint4*)d)[g] = ((const uint4*)s)[g];
    for (unsigned int i = ng * 8 + idx; i < nn; i += stride) d[i] = s[i];
  }
}

// ---------- bias table precompute: bias_full[h][n][m] fp32 ----------
__global__ __launch_bounds__(256) void bias_kernel(
    const unsigned short* __restrict__ cAb, const int* __restrict__ bias_idxs,
    float* __restrict__ bias_full) {
  const int h = blockIdx.x;
  for (int i = threadIdx.x; i < NTOK * NTOK; i += 256)
    bias_full[h * NTOK * NTOK + i] = bf2f(cAb[h * NTOK + bias_idxs[i]]);
}

// ---------- conv/BN table precompute: cwT[t][c] bf16, bn scale/shift fp32 ----------
__global__ __launch_bounds__(384) void prep_kernel(
    const unsigned short* __restrict__ cw, const unsigned short* __restrict__ bg,
    const unsigned short* __restrict__ bb, const unsigned short* __restrict__ bm,
    const unsigned short* __restrict__ bv,
    unsigned short* __restrict__ cwT, float* __restrict__ bnsc, float* __restrict__ bnsh) {
  const int c = threadIdx.x;
  const float sc = bf2f(bg[c]) * rsqrtf(bf2f(bv[c]) + EPS);
  bnsc[c] = sc;
  bnsh[c] = bf2f(bb[c]) - bf2f(bm[c]) * sc;
  #pragma unroll
  for (int t = 0; t < 9; ++t) cwT[t * CC + c] = cw[c * 9 + t];
}

// ---------- LayerNorm + window gather (pre-attention) ----------
__global__ __launch_bounds__(128) void ln_kernel(
    const unsigned short* __restrict__ x, const unsigned short* __restrict__ g,
    const unsigned short* __restrict__ b, unsigned short* __restrict__ out) {
  const int tid = threadIdx.x;
  int wi = blockIdx.y, n = blockIdx.x;
  int bb = wi >> 4, wb = wi & 15;
  int nh_i = wb >> 2, nw_i = wb & 3;
  int hs = n / 7, wsx = n - hs * 7;
  int l = nh_i * 196 + hs * 28 + nw_i * 7 + wsx;
  size_t src_row = (size_t)bb * LL + l;
  size_t dst_row = (size_t)wi * NTOK + n;
  const unsigned short* xr = x + src_row * CC;
  float vals[3]; float s = 0.f, sq = 0.f;
  for (int j = 0; j < 3; ++j) {
    vals[j] = bf2f(xr[tid + 128 * j]);
    s += vals[j]; sq += vals[j] * vals[j];
  }
  for (int off = 32; off; off >>= 1) { s += __shfl_xor(s, off); sq += __shfl_xor(sq, off); }
  __shared__ float red[4];
  const int wv = tid >> 6;
  if ((tid & 63) == 0) { red[wv] = s; red[2 + wv] = sq; }
  __syncthreads();
  float tot = red[0] + red[1], totq = red[2] + red[3];
  float mean = tot * (1.f / CC);
  float var = totq * (1.f / CC) - mean * mean;
  float inv = rsqrtf(var + EPS);
  unsigned short* orow = out + dst_row * CC;
  for (int j = 0; j < 3; ++j) {
    int c = tid + 128 * j;
    float y = (vals[j] - mean) * inv * bf2f(g[c]) + bf2f(b[c]);
    orow[c] = f2bf(y);
  }
}

// ---------- GEMM: 128x128 tile, 4 waves, 4x4 acc, BK=32 ----------
// K-loop: 3 LDS buffers (48 KB -> 3 blocks/CU), prefetch depth 2, counted
// vmcnt, and ONE s_barrier per K-step (was 2):
//   vmcnt(4) -> barrier -> stage(t+2) -> ds_read -> MFMA -> lgkmcnt(0)
// WAR safety: stage(t+2) overwrites buf[(t-1)%3]; every wave retired its
// reads of that buffer (lgkmcnt(0)) BEFORE reaching this iteration's
// barrier, and the stage issues only after the barrier -> no race.
// vmcnt: at the wait point only tiles t,t+1 are in flight (t+2 issues
// after the barrier) -> vmcnt(4) retires exactly tile t.
// T2 swizzle (both-sides, rule #21), corrected permutation p(fr) =
// (fr + (fr>>2)) & 3: bank-group 4*(fr&1) + (quad^p(fr)) is a bijection
// on every aligned 8-lane group -> conflict-free ds_read_b128.
// [R5 lesson: XOR with (fr&3) alone leaves fr/fr+4 colliding - measured
// no conflict reduction.]
// Grid: 1D, XCD-chunked bijective remap (m204) + N-fastest tile order
// (R4: fc2 FETCH 269 -> 117 MB; keep).
enum { EP_PLAIN = 0, EP_GELU = 1, EP_WINRES = 2, EP_RES2 = 3 };

template <int EP>
__global__ __launch_bounds__(256) void gemm128(
    const unsigned short* __restrict__ A, const unsigned short* __restrict__ W,
    const unsigned short* __restrict__ bias, const unsigned short* __restrict__ res,
    void* __restrict__ outp, int K, int N, int m_off, const int* __restrict__ flagp,
    int Nt) {
  __shared__ __align__(16) unsigned short lds[3 * 8192];  // 3 x (A 128x32 + B 128x32)
  const int tid = threadIdx.x;
  const int lane = tid & 63;
  const int wave = tid >> 6;
  // --- XCD-chunked bijective remap (m204), then N-fastest tile order ---
  const int nwg = gridDim.x;
  const int id = blockIdx.x;
  const int q8 = nwg >> 3, r8 = nwg & 7;
  const int xcd = id & 7, rank = id >> 3;
  const int wgid = (xcd < r8 ? xcd * (q8 + 1) : r8 * (q8 + 1) + (xcd - r8) * q8) + rank;
  const int bm = (wgid / Nt) * 128;
  const int bn = (wgid - (wgid / Nt) * Nt) * 128;
  const int wm = (wave >> 1) * 64;
  const int wn = (wave & 1) * 64;
  // staging: row = tid>>2 (0..63, +64 second half), granule c = tid&3.
  // source col XOR-permuted with p(row) = ((row&15) + ((row&15)>>2)) & 3;
  // LDS dest stays linear (tid*8) for global_load_lds.
  const int srow = tid >> 2;
  const int sr15 = srow & 15;
  const int sp = (sr15 + (sr15 >> 2)) & 3;
  const int s_col = ((tid & 3) ^ sp) * 8;   // swizzled source col (shorts)
  const unsigned short* Ap0 = A + (size_t)(bm + srow) * K + s_col;
  const unsigned short* Wp0 = W + (size_t)(bn + srow) * K + s_col;
  const size_t rstep = (size_t)64 * K;
  f32x4 acc[4][4] = {};
  const int fr = lane & 15;
  const int quad = lane >> 4;
  const int nt = K >> 5;   // K % 32 == 0 (384, 1536)
  const int rp = (fr + (fr >> 2)) & 3;
  const int cg = (quad ^ rp) * 8;          // conflict-free read granule

  auto stage = [&](int bsel, int t) {
    const unsigned short* ap = Ap0 + (size_t)t * 32;
    const unsigned short* wp = Wp0 + (size_t)t * 32;
    unsigned short* al = lds + bsel * 8192 + tid * 8;
    unsigned short* bl = al + 4096;
    gl_lds16(ap, al);
    gl_lds16(ap + rstep, al + 2048);
    gl_lds16(wp, bl);
    gl_lds16(wp + rstep, bl + 2048);
  };

  // prologue: tiles 0 and 1 in flight (8 outstanding loads per thread)
  stage(0, 0);
  stage(1, 1);
  int b = 0;
  for (int t = 0; t < nt; ++t) {
    // retire exactly tile t's 4 loads (t and t+1 in flight here)
    if (t + 1 < nt) asm volatile("s_waitcnt vmcnt(4)" ::: "memory");
    else            asm volatile("s_waitcnt vmcnt(0)" ::: "memory");
    __builtin_amdgcn_s_barrier();            // tile t resident; prior reads retired by all
    __builtin_amdgcn_sched_barrier(0);       // keep stage/ds_reads below the barrier
    if (t + 2 < nt) stage(b ? b - 1 : 2, t + 2);   // buf[(t+2)%3] == buf[(t-1)%3]
    const unsigned short* Ab = lds + b * 8192;
    const unsigned short* Bb = Ab + 4096;
    bf16x8 af[4], bfr[4];
    #pragma unroll
    for (int i = 0; i < 4; ++i) {
      af[i]  = *(const bf16x8*)(Ab + (wm + i * 16 + fr) * 32 + cg);
      bfr[i] = *(const bf16x8*)(Bb + (wn + i * 16 + fr) * 32 + cg);
    }
    #pragma unroll
    for (int i = 0; i < 4; ++i)
      #pragma unroll
      for (int j = 0; j < 4; ++j)
        acc[i][j] = __builtin_amdgcn_mfma_f32_16x16x32_bf16(af[i], bfr[j], acc[i][j], 0, 0, 0);
    asm volatile("s_waitcnt lgkmcnt(0)" ::: "memory");  // my reads of buf t retired
    __builtin_amdgcn_sched_barrier(0);
    b = (b == 2) ? 0 : b + 1;
  }

  int isf32 = 0;
  if (EP == EP_RES2) isf32 = *flagp;
  const int qr = (lane >> 4) * 4;
  float bvs[4];
  #pragma unroll
  for (int tj = 0; tj < 4; ++tj) bvs[tj] = bf2f(bias[bn + wn + tj * 16 + fr]);
  #pragma unroll
  for (int ti = 0; ti < 4; ++ti) {
    #pragma unroll
    for (int r = 0; r < 4; ++r) {
      const int mr = bm + wm + ti * 16 + qr + r;
      size_t rowbase;
      if (EP == EP_WINRES) {
        int wi = mr / 49; int nt2 = mr - wi * 49;
        int bb = wi >> 4; int wb = wi & 15;
        int nh_i = wb >> 2; int nw_i = wb & 3;
        int hs = nt2 / 7; int wsx = nt2 - hs * 7;
        int l = nh_i * 196 + hs * 28 + nw_i * 7 + wsx;
        rowbase = ((size_t)bb * LL + l) * CC;
      } else if (EP == EP_RES2) {
        rowbase = (size_t)(mr + m_off) * N;
      } else {
        rowbase = (size_t)mr * N;
      }
      #pragma unroll
      for (int tj = 0; tj < 4; ++tj) {
        const int n = bn + wn + tj * 16 + fr;
        float v = acc[ti][tj][r] + bvs[tj];
        if (EP == EP_GELU) {
          // gelu(x) = x * sigmoid(1.59576912x + 0.07135482x^3)
          const float t2 = v * (1.5957691216f + 0.0713548162f * v * v);
          v = __fdividef(v, 1.0f + __expf(-t2));
          ((unsigned short*)outp)[rowbase + n] = f2bf(v);
        } else if (EP == EP_WINRES) {
          size_t idx = rowbase + n;
          v += bf2f(res[idx]);
          ((unsigned short*)outp)[idx] = f2bf(v);
        } else if (EP == EP_RES2) {
          size_t idx = rowbase + n;
          v += bf2f(res[idx]);
          if (isf32) ((float*)outp)[idx] = v;
          else       ((unsigned short*)outp)[idx] = f2bf(v);
        } else {
          ((unsigned short*)outp)[rowbase + n] = f2bf(v);
        }
      }
    }
  }
}

// ---------- MFMA windowed attention: one WAVE per (window, head) ----------
__global__ __launch_bounds__(64) void attn_mfma(
    const unsigned short* __restrict__ qkv, const float* __restrict__ bias_full,
    unsigned short* __restrict__ o, int wi_off) {
  __shared__ __align__(16) unsigned short Pl[64 * 72];
  __shared__ __align__(16) unsigned short vT[32 * 72];
  const int wi = blockIdx.x, h = blockIdx.y;
  const int lane = threadIdx.x;
  const int l15 = lane & 15;
  const int quad = lane >> 4;
  const unsigned short* base = qkv + (size_t)wi * NTOK * QKV_OUT + h * 96;

  bf16x8 qf[4], kf[4];
  #pragma unroll
  for (int i = 0; i < 4; ++i) {
    const int n = i * 16 + l15;
    if (n < NTOK) {
      const unsigned short* p = base + (size_t)n * QKV_OUT + quad * 8;
      qf[i] = *(const bf16x8*)(p);
      kf[i] = *(const bf16x8*)(p + 32);
    } else {
      qf[i] = (bf16x8)0; kf[i] = (bf16x8)0;
    }
  }

  for (int idx = lane; idx < 32 * 72; idx += 64) vT[idx] = 0;
  __syncthreads();
  for (int idx = lane; idx < NTOK * KD; idx += 64) {
    const int m = idx >> 5, d = idx & 31;
    vT[d * 72 + m] = base[(size_t)m * QKV_OUT + 64 + d];
  }

  f32x4 acc[4][4] = {};
  #pragma unroll
  for (int i = 0; i < 4; ++i)
    #pragma unroll
    for (int j = 0; j < 4; ++j)
      acc[i][j] = __builtin_amdgcn_mfma_f32_16x16x32_bf16(qf[i], kf[j], acc[i][j], 0, 0, 0);

  const float* bh = bias_full + h * NTOK * NTOK;
  float rinv[4][4];
  #pragma unroll
  for (int i = 0; i < 4; ++i) {
    #pragma unroll
    for (int r = 0; r < 4; ++r) {
      const int n = i * 16 + quad * 4 + r;
      float sv[4];
      #pragma unroll
      for (int j = 0; j < 4; ++j) {
        const int m = j * 16 + l15;
        float s = acc[i][j][r] * SCALE;
        if (n < NTOK && m < NTOK) s += bh[n * NTOK + m];
        if (m >= NTOK) s = -1e30f;
        sv[j] = s;
      }
      float mx = fmaxf(fmaxf(sv[0], sv[1]), fmaxf(sv[2], sv[3]));
      #pragma unroll
      for (int t = 1; t < 16; t <<= 1) mx = fmaxf(mx, __shfl_xor(mx, t));
      float sum = 0.f;
      #pragma unroll
      for (int j = 0; j < 4; ++j) {
        const float p = __expf(sv[j] - mx);
        sum += p;
        Pl[n * 72 + j * 16 + l15] = f2bf(p);
      }
      #pragma unroll
      for (int t = 1; t < 16; t <<= 1) sum += __shfl_xor(sum, t);
      rinv[i][r] = 1.f / sum;
    }
  }
  __syncthreads();

  f32x4 acc2[4][2] = {};
  #pragma unroll
  for (int kk = 0; kk < 2; ++kk) {
    bf16x8 pf[4], vf[2];
    #pragma unroll
    for (int i = 0; i < 4; ++i)
      pf[i] = *(const bf16x8*)(Pl + (i * 16 + l15) * 72 + kk * 32 + quad * 8);
    #pragma unroll
    for (int jd = 0; jd < 2; ++jd)
      vf[jd] = *(const bf16x8*)(vT + (jd * 16 + l15) * 72 + kk * 32 + quad * 8);
    #pragma unroll
    for (int i = 0; i < 4; ++i)
      #pragma unroll
      for (int jd = 0; jd < 2; ++jd)
        acc2[i][jd] = __builtin_amdgcn_mfma_f32_16x16x32_bf16(pf[i], vf[jd], acc2[i][jd], 0, 0, 0);
  }

  #pragma unroll
  for (int i = 0; i < 4; ++i) {
    #pragma unroll
    for (int r = 0; r < 4; ++r) {
      const int n = i * 16 + quad * 4 + r;
      if (n < NTOK) {
        const float ri = rinv[i][r];
        #pragma unroll
        for (int jd = 0; jd < 2; ++jd) {
          const int d = jd * 16 + l15;
          o[((size_t)(wi_off + wi) * NTOK + n) * CC + h * KD + d] = f2bf(acc2[i][jd][r] * ri);
        }
      }
    }
  }
}

// ---------- fused depthwise 3x3 conv + BN + LN_m ----------
__global__ __launch_bounds__(384) void conv_bn_ln(
    const unsigned short* __restrict__ x1, const unsigned short* __restrict__ cwT,
    const float* __restrict__ bnsc, const float* __restrict__ bnsh,
    const unsigned short* __restrict__ mg, const unsigned short* __restrict__ mb,
    unsigned short* __restrict__ x2, unsigned short* __restrict__ xm) {
  __shared__ float rs[8][48], rq[8][48];
  const int tid = threadIdx.x;
  const int pos = tid / 48;
  const int c8 = tid - pos * 48;
  const int c0 = c8 * 8;
  const int hw = blockIdx.x * 8 + pos;
  const int b = blockIdx.y;
  const int h = hw / 28, w = hw - h * 28;
  float acc[8] = {};
  #pragma unroll
  for (int t = 0; t < 9; ++t) {
    const int dh = t / 3 - 1, dw = t % 3 - 1;
    const int hh = h + dh, ww = w + dw;
    if (hh >= 0 && hh < 28 && ww >= 0 && ww < 28) {
      const uint4 xv = *(const uint4*)(x1 + ((size_t)b * LL + hh * 28 + ww) * CC + c0);
      const uint4 wv = *(const uint4*)(cwT + t * CC + c0);
      const unsigned short* xp = (const unsigned short*)&xv;
      const unsigned short* wp = (const unsigned short*)&wv;
      #pragma unroll
      for (int k = 0; k < 8; ++k) acc[k] += bf2f(xp[k]) * bf2f(wp[k]);
    }
  }
  const float4 sc0 = *(const float4*)(bnsc + c0);
  const float4 sc1 = *(const float4*)(bnsc + c0 + 4);
  const float4 sh0 = *(const float4*)(bnsh + c0);
  const float4 sh1 = *(const float4*)(bnsh + c0 + 4);
  float y[8];
  y[0] = acc[0] * sc0.x + sh0.x; y[1] = acc[1] * sc0.y + sh0.y;
  y[2] = acc[2] * sc0.z + sh0.z; y[3] = acc[3] * sc0.w + sh0.w;
  y[4] = acc[4] * sc1.x + sh1.x; y[5] = acc[5] * sc1.y + sh1.y;
  y[6] = acc[6] * sc1.z + sh1.z; y[7] = acc[7] * sc1.w + sh1.w;
  ushort4 pk0, pk1;
  pk0.x = f2bf(y[0]); pk0.y = f2bf(y[1]); pk0.z = f2bf(y[2]); pk0.w = f2bf(y[3]);
  pk1.x = f2bf(y[4]); pk1.y = f2bf(y[5]); pk1.z = f2bf(y[6]); pk1.w = f2bf(y[7]);
  const size_t row = ((size_t)b * LL + hw) * CC + c0;
  *(ushort4*)(x2 + row) = pk0;
  *(ushort4*)(x2 + row + 4) = pk1;
  float s = 0.f, q = 0.f;
  #pragma unroll
  for (int k = 0; k < 8; ++k) { s += y[k]; q += y[k] * y[k]; }
  rs[pos][c8] = s; rq[pos][c8] = q;
  __syncthreads();
  float tot = 0.f, tq = 0.f;
  #pragma unroll 8
  for (int i = 0; i < 48; ++i) { tot += rs[pos][i]; tq += rq[pos][i]; }
  const float mean = tot * (1.f / CC);
  const float var = tq * (1.f / CC) - mean * mean;
  const float inv = rsqrtf(var + EPS);
  const uint4 gv = *(const uint4*)(mg + c0);
  const uint4 bv = *(const uint4*)(mb + c0);
  const unsigned short* gp = (const unsigned short*)&gv;
  const unsigned short* bp = (const unsigned short*)&bv;
  ushort4 lo, hi;
  unsigned short outv[8];
  #pragma unroll
  for (int k = 0; k < 8; ++k)
    outv[k] = f2bf((y[k] - mean) * inv * bf2f(gp[k]) + bf2f(bp[k]));
  lo.x = outv[0]; lo.y = outv[1]; lo.z = outv[2]; lo.w = outv[3];
  hi.x = outv[4]; hi.y = outv[5]; hi.z = outv[6]; hi.w = outv[7];
  *(ushort4*)(xm + row) = lo;
  *(ushort4*)(xm + row + 4) = hi;
}

// ---------- launch ----------
extern "C" void kernel_launch(void* const* d_in, const int* in_sizes, int n_in,
                              void* d_out, int out_size, void* d_ws, size_t ws_size,
                              hipStream_t stream) {
  int* flag = (int*)d_ws;
  unsigned short* base = (unsigned short*)d_ws;

  CvtArgs args;
  size_t cur = 32;
  size_t off[19];
  for (int i = 0; i < 19; ++i) {
    off[i] = cur;
    args.src[i] = d_in[i];
    args.n[i] = (unsigned int)in_sizes[i];
    args.off[i] = (unsigned int)cur;
    cur += ((size_t)in_sizes[i] + 63) & ~(size_t)63;
  }
  const unsigned short* cx   = base + off[0];
  const unsigned short* cgA  = base + off[1];
  const unsigned short* cbA  = base + off[2];
  const unsigned short* cQw  = base + off[3];
  const unsigned short* cQb  = base + off[4];
  const unsigned short* cAb  = base + off[5];
  const unsigned short* cPw  = base + off[6];
  const unsigned short* cPb  = base + off[7];
  const unsigned short* cCw  = base + off[8];
  const unsigned short* cBg  = base + off[9];
  const unsigned short* cBb  = base + off[10];
  const unsigned short* cBm  = base + off[11];
  const unsigned short* cBv  = base + off[12];
  const unsigned short* cMg  = base + off[13];
  const unsigned short* cMb  = base + off[14];
  const unsigned short* cF1w = base + off[15];
  const unsigned short* cF1b = base + off[16];
  const unsigned short* cF2w = base + off[17];
  const unsigned short* cF2b = base + off[18];
  const int* bias_idxs = (const int*)d_in[19];

  const size_t SZ = (size_t)MTOT * CC;             // 19267584 elems
  // chunking: merge M-halves into one launch if workspace permits.
  const size_t need_full_bytes =
      (cur + SZ + (size_t)MTOT * HID) * 2 + 512 * 1024;
  const int nchunk = (ws_size >= need_full_bytes) ? 1 : 2;
  const int MC = MTOT / nchunk;                    // GEMM rows per chunk
  const int WC = 1024 / nchunk;                    // windows per chunk
  const size_t buf2_cap = (size_t)MC * HID;

  unsigned short* o_buf = base + cur;               // attn out o; later xm
  unsigned short* buf2  = o_buf + SZ;               // qkv chunk / h chunk
  unsigned short* x2    = base + off[0];            // conv+BN out overwrites spent cx
  float* bias_full = (float*)(buf2 + buf2_cap);     // [12][49][49] f32
  unsigned short* cwT = (unsigned short*)(bias_full + 12 * NTOK * NTOK);  // [9][384] bf16
  float* bnsc = (float*)(cwT + 9 * CC);
  float* bnsh = bnsc + CC;

  unsigned short* xn = (unsigned short*)d_out;

  // 0. dtype detect + canonicalize + tables
  detect_kernel<<<1, 256, 0, stream>>>((const unsigned short*)d_in[0], flag);
  convert_kernel<<<dim3(512, 19), 256, 0, stream>>>(args, base, flag);
  bias_kernel<<<NHEAD, 256, 0, stream>>>(cAb, bias_idxs, bias_full);
  prep_kernel<<<1, 384, 0, stream>>>(cCw, cBg, cBb, cBm, cBv, cwT, bnsc, bnsh);

  // 1. window partition + LN_a -> xn (d_out)
  ln_kernel<<<dim3(49, 1024), 128, 0, stream>>>(cx, cgA, cbA, xn);

  // 2+3. qkv projection + MFMA attention
  for (int c = 0; c < nchunk; ++c) {
    gemm128<EP_PLAIN><<<(MC / 128) * (QKV_OUT / 128), 256, 0, stream>>>(
        xn + (size_t)c * MC * CC, cQw, cQb, nullptr, buf2, CC, QKV_OUT, 0, nullptr,
        QKV_OUT / 128);
    attn_mfma<<<dim3(WC, NHEAD), 64, 0, stream>>>(buf2, bias_full, o_buf, c * WC);
  }

  // 4. proj + un-window + residual(x) -> x1 (d_out)
  gemm128<EP_WINRES><<<(MTOT / 128) * (CC / 128), 256, 0, stream>>>(
      o_buf, cPw, cPb, cx, d_out, CC, CC, 0, nullptr, CC / 128);

  // 5. fused conv + BN + LN_m -> x2 (residual) and xm (o_buf, fc1 input)
  conv_bn_ln<<<dim3(98, BATCH), 384, 0, stream>>>(
      (const unsigned short*)d_out, cwT, bnsc, bnsh, cMg, cMb, x2, o_buf);

  // 6+7. MLP; fc2 writes final output
  for (int c = 0; c < nchunk; ++c) {
    gemm128<EP_GELU><<<(MC / 128) * (HID / 128), 256, 0, stream>>>(
        o_buf + (size_t)c * MC * CC, cF1w, cF1b, nullptr, buf2, CC, HID, 0, nullptr,
        HID / 128);
    gemm128<EP_RES2><<<(MC / 128) * (CC / 128), 256, 0, stream>>>(
        buf2, cF2w, cF2b, x2, d_out, HID, CC, c * MC, flag, CC / 128);
  }
}